// Round 6
// baseline (125.381 us; speedup 1.0000x reference)
//
#include <hip/hip_runtime.h>
#include <hip/hip_bf16.h>
#include <math.h>

#define B 4
#define T 128
#define C 512
#define NH 8
#define HS 64
#define BH (B*NH)   // 32

typedef __attribute__((ext_vector_type(8))) short bf16x8;
typedef __attribute__((ext_vector_type(4))) float f32x4;

__device__ __forceinline__ unsigned short bfc(float x) {
    return __builtin_bit_cast(unsigned short, __float2bfloat16(x));
}
__device__ __forceinline__ unsigned int pk_bf16(float a, float b) {
    return (unsigned int)bfc(a) | ((unsigned int)bfc(b) << 16);
}
__device__ __forceinline__ float lo_f(unsigned int g) {
    return __builtin_bit_cast(float, g << 16);
}
__device__ __forceinline__ float hi_f(unsigned int g) {
    return __builtin_bit_cast(float, g & 0xffff0000u);
}

// ---------------- K1: p{0,1,2} = X @ Wp{0,1,2}  (fp32 in, bf16 out, on-the-fly cvt+transpose)
// z==2 additionally emits rr = rowsums(p2).
__global__ __launch_bounds__(256) void proj_kernel(
    const float* __restrict__ X,
    const float* __restrict__ Wp0, const float* __restrict__ Wp1, const float* __restrict__ Wp2,
    unsigned short* __restrict__ p0b, unsigned short* __restrict__ p1b,
    unsigned short* __restrict__ p2b, float* __restrict__ rr)
{
    __shared__ __align__(16) unsigned short As[64][72];
    __shared__ __align__(16) unsigned short Bs[64][72];
    __shared__ float Ls[64][69];
    __shared__ float sRS[4][64];
    const int z = blockIdx.z;
    const float* W = (z == 0) ? Wp0 : (z == 1) ? Wp1 : Wp2;
    const int m0 = blockIdx.y * 64, n0 = blockIdx.x * 64;
    const int tid = threadIdx.x;
    const int w = tid >> 6, lane = tid & 63, quad = lane >> 4, l16 = lane & 15;
    f32x4 acc[4];
    #pragma unroll
    for (int mt = 0; mt < 4; ++mt) acc[mt] = (f32x4){0.f, 0.f, 0.f, 0.f};

    for (int k0 = 0; k0 < 512; k0 += 64) {
        __syncthreads();
        #pragma unroll
        for (int it = 0; it < 2; ++it) {
            const int q = tid + it * 256;
            const int row = q >> 3, c8 = (q & 7) * 8;
            const float4 a = *(const float4*)&X[(size_t)(m0 + row) * 512 + k0 + c8];
            const float4 b = *(const float4*)&X[(size_t)(m0 + row) * 512 + k0 + c8 + 4];
            uint4 o;
            o.x = pk_bf16(a.x, a.y);
            o.y = pk_bf16(a.z, a.w);
            o.z = pk_bf16(b.x, b.y);
            o.w = pk_bf16(b.z, b.w);
            *(uint4*)&As[row][c8] = o;
        }
        #pragma unroll
        for (int it = 0; it < 4; ++it) {
            const int q = tid + it * 256;
            const int row = q >> 4, c4 = (q & 15) * 4;
            const float4 v = *(const float4*)&W[(size_t)(k0 + row) * 512 + n0 + c4];
            Ls[row][c4 + 0] = v.x; Ls[row][c4 + 1] = v.y;
            Ls[row][c4 + 2] = v.z; Ls[row][c4 + 3] = v.w;
        }
        __syncthreads();
        #pragma unroll
        for (int it = 0; it < 2; ++it) {
            const int q = tid + it * 256;
            const int nrow = q >> 3, k8 = (q & 7) * 8;
            uint4 o;
            o.x = pk_bf16(Ls[k8 + 0][nrow], Ls[k8 + 1][nrow]);
            o.y = pk_bf16(Ls[k8 + 2][nrow], Ls[k8 + 3][nrow]);
            o.z = pk_bf16(Ls[k8 + 4][nrow], Ls[k8 + 5][nrow]);
            o.w = pk_bf16(Ls[k8 + 6][nrow], Ls[k8 + 7][nrow]);
            *(uint4*)&Bs[nrow][k8] = o;
        }
        __syncthreads();
        #pragma unroll
        for (int kt = 0; kt < 2; ++kt) {
            const bf16x8 b8 = *(const bf16x8*)&Bs[w * 16 + l16][kt * 32 + quad * 8];
            #pragma unroll
            for (int mt = 0; mt < 4; ++mt) {
                const bf16x8 a8 = *(const bf16x8*)&As[mt * 16 + l16][kt * 32 + quad * 8];
                acc[mt] = __builtin_amdgcn_mfma_f32_16x16x32_bf16(a8, b8, acc[mt], 0, 0, 0);
            }
        }
    }

    {
        const int n = n0 + w * 16 + l16;
        const int h = n >> 6, d = n & 63;
        unsigned short* pz = (z == 0) ? p0b : (z == 1) ? p1b : p2b;
        #pragma unroll
        for (int mt = 0; mt < 4; ++mt) {
            #pragma unroll
            for (int r = 0; r < 4; ++r) {
                const int m = m0 + mt * 16 + quad * 4 + r;
                const int bb = m >> 7, t = m & 127;
                pz[((size_t)(bb * NH + h) * T + t) * HS + d] = bfc(acc[mt][r]);
            }
        }
    }
    if (z == 2) {
        #pragma unroll
        for (int mt = 0; mt < 4; ++mt)
            #pragma unroll
            for (int r = 0; r < 4; ++r) {
                float v = acc[mt][r];
                v += __shfl_xor(v, 1, 64); v += __shfl_xor(v, 2, 64);
                v += __shfl_xor(v, 4, 64); v += __shfl_xor(v, 8, 64);
                if (l16 == 0) sRS[w][mt * 16 + quad * 4 + r] = v;
            }
        __syncthreads();
        if (tid < 64) {
            const float s = sRS[0][tid] + sRS[1][tid] + sRS[2][tid] + sRS[3][tid];
            const int m = m0 + tid, bb = m >> 7, tl = m & 127, h = n0 >> 6;
            rr[(bb * NH + h) * T + tl] = s;
        }
    }
}

// ---------------- K2: attention; 1024 blocks = (bh, ig 0..31) x 4 i's; ~34.5 KB LDS -> 4 blocks/CU
__global__ __launch_bounds__(256) void attn_kernel(
    const unsigned short* __restrict__ p0b, const unsigned short* __restrict__ p1b,
    const unsigned short* __restrict__ p2b, const float* __restrict__ rr,
    const float* __restrict__ Wv0, const float* __restrict__ Wv1,
    unsigned short* __restrict__ Yb)
{
    __shared__ __align__(16) union {
        struct {
            unsigned short sWv[64][72];      // Wv^T bf16 [d][k] (one at a time)
            unsigned short sVst[64][136];    // V^T staging [d][t] (reused V0 then V1)
        } v;                                  // 26.6 KB
        unsigned short sE[128 * 128];        // full-width E, xor-swizzled 16B chunks; 32 KB
    } u;
    __shared__ float sS[4][128];
    __shared__ float srr[128];
    __shared__ float sZ[4];

    const int bid = blockIdx.x;
    const int bh = bid & (BH - 1);
    const int ig = bid >> 5;                 // 0..31
    const int tid = threadIdx.x;
    const int w = tid >> 6;
    const int lane = tid & 63;
    const int quad = lane >> 4;
    const int l16 = lane & 15;

    if (tid < 128) srr[tid] = rr[bh * T + tid];

    // ---- stage Wv0^T ----
    #pragma unroll
    for (int it = 0; it < 4; ++it) {
        const int k = (tid >> 4) + it * 16;
        const int d0 = (tid & 15) * 4;
        const float4 wv = *(const float4*)&Wv0[(size_t)k * 64 + d0];
        u.v.sWv[d0 + 0][k] = bfc(wv.x); u.v.sWv[d0 + 1][k] = bfc(wv.y);
        u.v.sWv[d0 + 2][k] = bfc(wv.z); u.v.sWv[d0 + 3][k] = bfc(wv.w);
    }
    __syncthreads();                                       // sWv(Wv0) + srr ready

    // ---- V0 = p1 @ Wv0 -> sVst (D[m=d][n=t], K=64) ----
    #pragma unroll
    for (int nn = 0; nn < 2; ++nn) {
        const int nt = w + nn * 4;
        f32x4 vacc[4];
        #pragma unroll
        for (int mt = 0; mt < 4; ++mt) vacc[mt] = (f32x4){0.f, 0.f, 0.f, 0.f};
        #pragma unroll
        for (int kt = 0; kt < 2; ++kt) {
            const bf16x8 b8 = *(const bf16x8*)&p1b[((size_t)bh * T + nt * 16 + l16) * HS + kt * 32 + quad * 8];
            #pragma unroll
            for (int mt = 0; mt < 4; ++mt) {
                const bf16x8 a8 = *(const bf16x8*)&u.v.sWv[mt * 16 + l16][kt * 32 + quad * 8];
                vacc[mt] = __builtin_amdgcn_mfma_f32_16x16x32_bf16(a8, b8, vacc[mt], 0, 0, 0);
            }
        }
        #pragma unroll
        for (int mt = 0; mt < 4; ++mt)
            #pragma unroll
            for (int r = 0; r < 4; ++r)
                u.v.sVst[mt * 16 + quad * 4 + r][nt * 16 + l16] = bfc(vacc[mt][r]);
    }
    __syncthreads();                                       // sVst(V0) ready

    // ---- v0 regs (wave's own d-slice) + stage Wv1^T ----
    uint2 v0r[8];
    #pragma unroll
    for (int mt = 0; mt < 8; ++mt)
        v0r[mt] = *(const uint2*)&u.v.sVst[(w << 4) + l16][(mt << 4) + (quad << 2)];
    #pragma unroll
    for (int it = 0; it < 4; ++it) {
        const int k = (tid >> 4) + it * 16;
        const int d0 = (tid & 15) * 4;
        const float4 wv = *(const float4*)&Wv1[(size_t)k * 64 + d0];
        u.v.sWv[d0 + 0][k] = bfc(wv.x); u.v.sWv[d0 + 1][k] = bfc(wv.y);
        u.v.sWv[d0 + 2][k] = bfc(wv.z); u.v.sWv[d0 + 3][k] = bfc(wv.w);
    }
    __syncthreads();                                       // v0r loaded + sWv(Wv1) ready

    // ---- V1 = p2 @ Wv1 -> sVst ----
    #pragma unroll
    for (int nn = 0; nn < 2; ++nn) {
        const int nt = w + nn * 4;
        f32x4 vacc[4];
        #pragma unroll
        for (int mt = 0; mt < 4; ++mt) vacc[mt] = (f32x4){0.f, 0.f, 0.f, 0.f};
        #pragma unroll
        for (int kt = 0; kt < 2; ++kt) {
            const bf16x8 b8 = *(const bf16x8*)&p2b[((size_t)bh * T + nt * 16 + l16) * HS + kt * 32 + quad * 8];
            #pragma unroll
            for (int mt = 0; mt < 4; ++mt) {
                const bf16x8 a8 = *(const bf16x8*)&u.v.sWv[mt * 16 + l16][kt * 32 + quad * 8];
                vacc[mt] = __builtin_amdgcn_mfma_f32_16x16x32_bf16(a8, b8, vacc[mt], 0, 0, 0);
            }
        }
        #pragma unroll
        for (int mt = 0; mt < 4; ++mt)
            #pragma unroll
            for (int r = 0; r < 4; ++r)
                u.v.sVst[mt * 16 + quad * 4 + r][nt * 16 + l16] = bfc(vacc[mt][r]);
    }
    __syncthreads();                                       // sVst(V1) ready

    // ---- v1r regs ----
    uint4 v1r[4];
    #pragma unroll
    for (int kt = 0; kt < 4; ++kt)
        v1r[kt] = *(const uint4*)&u.v.sVst[(w << 4) + l16][(quad << 3) + (kt << 5)];

    // ---- S rows (4 of them) in one MFMA pass: A rows 0..3 = p0[i_q], rows 4..15 duplicates ----
    {
        const int qr = l16 & 3;
        const int irow = (qr & 1) ? (32 * qr + 31 - ig) : (32 * qr + ig);
        const unsigned short* ap = p0b + ((size_t)bh * T + irow) * HS + (quad << 3);
        const unsigned short* bp = p1b + (size_t)bh * T * HS + (quad << 3);
        f32x4 s0 = (f32x4){0.f, 0.f, 0.f, 0.f};
        f32x4 s1 = (f32x4){0.f, 0.f, 0.f, 0.f};
        #pragma unroll
        for (int kt = 0; kt < 2; ++kt) {
            const bf16x8 a8 = *(const bf16x8*)(ap + (kt << 5));
            const bf16x8 b0 = *(const bf16x8*)(bp + (size_t)((w << 5) + l16) * HS + (kt << 5));
            const bf16x8 b1 = *(const bf16x8*)(bp + (size_t)((w << 5) + 16 + l16) * HS + (kt << 5));
            s0 = __builtin_amdgcn_mfma_f32_16x16x32_bf16(a8, b0, s0, 0, 0, 0);
            s1 = __builtin_amdgcn_mfma_f32_16x16x32_bf16(a8, b1, s1, 0, 0, 0);
        }
        if (quad == 0) {
            #pragma unroll
            for (int r = 0; r < 4; ++r) {
                sS[r][(w << 5) + l16]      = s0[r] * 0.125f;
                sS[r][(w << 5) + 16 + l16] = s1[r] * 0.125f;
            }
        }
    }
    __syncthreads();                                       // v1r reads drained; sS ready; sE usable

    const float L2E = 1.4426950408889634f;

    for (int qq = 3; qq >= 0; --qq) {                      // biggest i first
        const int i = (qq & 1) ? (32 * qq + 31 - ig) : (32 * qq + ig);
        const float* sSq = sS[qq];

        // mhat: each wave computes the full [0..i] abs-max itself
        float mhat;
        {
            float a0 = (lane <= i) ? fabsf(sSq[lane]) : 0.f;
            float a1 = (64 + lane <= i) ? fabsf(sSq[64 + lane]) : 0.f;
            float r0 = (lane <= i) ? fabsf(srr[lane]) : 0.f;
            float r1 = (64 + lane <= i) ? fabsf(srr[64 + lane]) : 0.f;
            float aS = fmaxf(a0, a1), aR = fmaxf(r0, r1);
            #pragma unroll
            for (int off = 32; off; off >>= 1) {
                aS = fmaxf(aS, __shfl_xor(aS, off, 64));
                aR = fmaxf(aR, __shfl_xor(aR, off, 64));
            }
            mhat = aS * aR;
        }

        const float bexp = -mhat * L2E;
        const int mtmax = i >> 4;
        const int cc = tid & 15;           // 16B chunk (8 bf16 cols) of the 128-col row
        const int rowin = tid >> 4;        // row within 16-row pass
        const int k0l = cc << 3;
        float zacc = 0.f;

        // ---- full-width E build: rows 0..16*(mtmax+1)-1, cols 0..127 ----
        float rk[8];
        *(float4*)&rk[0] = *(const float4*)&srr[k0l];
        *(float4*)&rk[4] = *(const float4*)&srr[k0l + 4];
        const int npass = mtmax + 1;
        for (int p = 0; p < npass; ++p) {
            const int jj = (p << 4) + rowin;
            uint4 o = {0u, 0u, 0u, 0u};
            if (jj <= i && k0l <= jj) {
                const float aL = sSq[jj] * L2E;
                const int dlim = jj - k0l;
                float e[8];
                #pragma unroll
                for (int q = 0; q < 8; ++q) {
                    const float ex = __builtin_amdgcn_exp2f(fmaf(aL, rk[q], bexp));
                    e[q] = (q <= dlim) ? ex : 0.f;
                    zacc += e[q];
                }
                o.x = pk_bf16(e[0], e[1]);
                o.y = pk_bf16(e[2], e[3]);
                o.z = pk_bf16(e[4], e[5]);
                o.w = pk_bf16(e[6], e[7]);
            }
            *(uint4*)&u.sE[(jj << 7) + ((cc ^ (jj & 7)) << 3)] = o;
        }
        #pragma unroll
        for (int off = 32; off; off >>= 1) zacc += __shfl_xor(zacc, off, 64);
        if (lane == 0) sZ[w] = zacc;
        __syncthreads();                                   // E + Z ready

        // ---- PV MFMA: all row-tiles, all k-tiles (kt <= mt>>1) ----
        f32x4 acc[8];
        #pragma unroll
        for (int mt = 0; mt < 8; ++mt) acc[mt] = (f32x4){0.f, 0.f, 0.f, 0.f};
        #pragma unroll
        for (int mt = 0; mt < 8; ++mt) {
            if (mt <= mtmax) {
                #pragma unroll
                for (int kt = 0; kt < 4; ++kt) {
                    if (kt <= (mt >> 1)) {
                        const int ch = ((kt << 2) + quad) ^ (l16 & 7);
                        const bf16x8 a8 = *(const bf16x8*)&u.sE[(((mt << 4) + l16) << 7) + (ch << 3)];
                        acc[mt] = __builtin_amdgcn_mfma_f32_16x16x32_bf16(
                            a8, __builtin_bit_cast(bf16x8, v1r[kt]), acc[mt], 0, 0, 0);
                    }
                }
            }
        }
        const float Z = sZ[0] + sZ[1] + sZ[2] + sZ[3];

        // ---- epilogue: y[d] = sum_j V0[j][d]*Tmat[j][d] / Z ; V0 in regs ----
        float part = 0.f;
        #pragma unroll
        for (int mt = 0; mt < 8; ++mt) {
            if (mt < mtmax) {
                const uint2 uu = v0r[mt];
                part = fmaf(lo_f(uu.x), acc[mt][0], part);
                part = fmaf(hi_f(uu.x), acc[mt][1], part);
                part = fmaf(lo_f(uu.y), acc[mt][2], part);
                part = fmaf(hi_f(uu.y), acc[mt][3], part);
            } else if (mt == mtmax) {
                const uint2 uu = v0r[mt];
                const int jb = (mt << 4) + (quad << 2);
                if (jb + 0 <= i) part = fmaf(lo_f(uu.x), acc[mt][0], part);
                if (jb + 1 <= i) part = fmaf(hi_f(uu.x), acc[mt][1], part);
                if (jb + 2 <= i) part = fmaf(lo_f(uu.y), acc[mt][2], part);
                if (jb + 3 <= i) part = fmaf(hi_f(uu.y), acc[mt][3], part);
            }
        }
        part += __shfl_xor(part, 16, 64);
        part += __shfl_xor(part, 32, 64);
        if (lane < 16) {
            const int bb = bh >> 3, hh = bh & 7;
            Yb[((size_t)(bb * T + i) * C) + hh * HS + (w << 4) + l16] = bfc(part / Z);
        }
        __syncthreads();                                   // drain sE/sZ before next i
    }
}

// ---------------- K3: OUT = Yb @ Wc (bf16 A, fp32 W transposed on the fly, fp32 out)
__global__ __launch_bounds__(256) void outmm_kernel(
    const unsigned short* __restrict__ Ab, const float* __restrict__ Wc,
    float* __restrict__ OUT)
{
    __shared__ __align__(16) unsigned short As[64][72];
    __shared__ __align__(16) unsigned short Bs[64][72];
    __shared__ float Ls[64][69];
    const int m0 = blockIdx.y * 64, n0 = blockIdx.x * 64;
    const int tid = threadIdx.x;
    const int w = tid >> 6, lane = tid & 63, quad = lane >> 4, l16 = lane & 15;
    f32x4 acc[4];
    #pragma unroll
    for (int mt = 0; mt < 4; ++mt) acc[mt] = (f32x4){0.f, 0.f, 0.f, 0.f};
    for (int k0 = 0; k0 < 512; k0 += 64) {
        __syncthreads();
        #pragma unroll
        for (int it = 0; it < 2; ++it) {
            const int q = tid + it * 256;
            const int row = q >> 3, c8 = (q & 7) * 8;
            *(uint4*)&As[row][c8] = *(const uint4*)&Ab[(size_t)(m0 + row) * 512 + k0 + c8];
        }
        #pragma unroll
        for (int it = 0; it < 4; ++it) {
            const int q = tid + it * 256;
            const int row = q >> 4, c4 = (q & 15) * 4;
            const float4 v = *(const float4*)&Wc[(size_t)(k0 + row) * 512 + n0 + c4];
            Ls[row][c4 + 0] = v.x; Ls[row][c4 + 1] = v.y;
            Ls[row][c4 + 2] = v.z; Ls[row][c4 + 3] = v.w;
        }
        __syncthreads();
        #pragma unroll
        for (int it = 0; it < 2; ++it) {
            const int q = tid + it * 256;
            const int nrow = q >> 3, k8 = (q & 7) * 8;
            uint4 o;
            o.x = pk_bf16(Ls[k8 + 0][nrow], Ls[k8 + 1][nrow]);
            o.y = pk_bf16(Ls[k8 + 2][nrow], Ls[k8 + 3][nrow]);
            o.z = pk_bf16(Ls[k8 + 4][nrow], Ls[k8 + 5][nrow]);
            o.w = pk_bf16(Ls[k8 + 6][nrow], Ls[k8 + 7][nrow]);
            *(uint4*)&Bs[nrow][k8] = o;
        }
        __syncthreads();
        #pragma unroll
        for (int kt = 0; kt < 2; ++kt) {
            const bf16x8 b8 = *(const bf16x8*)&Bs[w * 16 + l16][kt * 32 + quad * 8];
            #pragma unroll
            for (int mt = 0; mt < 4; ++mt) {
                const bf16x8 a8 = *(const bf16x8*)&As[mt * 16 + l16][kt * 32 + quad * 8];
                acc[mt] = __builtin_amdgcn_mfma_f32_16x16x32_bf16(a8, b8, acc[mt], 0, 0, 0);
            }
        }
    }
    const int n = n0 + w * 16 + l16;
    #pragma unroll
    for (int mt = 0; mt < 4; ++mt)
        #pragma unroll
        for (int r = 0; r < 4; ++r) {
            const int mrow = m0 + mt * 16 + quad * 4 + r;
            OUT[(size_t)mrow * 512 + n] = acc[mt][r];
        }
}

extern "C" void kernel_launch(void* const* d_in, const int* in_sizes, int n_in,
                              void* d_out, int out_size, void* d_ws, size_t ws_size,
                              hipStream_t stream)
{
    const float* x   = (const float*)d_in[0];
    const float* Wp0 = (const float*)d_in[1];
    const float* Wp1 = (const float*)d_in[2];
    const float* Wp2 = (const float*)d_in[3];
    const float* Wv0 = (const float*)d_in[4];
    const float* Wv1 = (const float*)d_in[5];
    const float* Wc  = (const float*)d_in[6];
    float* out = (float*)d_out;

    char* w8 = (char*)d_ws;
    const size_t HB = 512 * 1024;
    unsigned short* p0b = (unsigned short*)(w8 + 0 * HB);
    unsigned short* p1b = (unsigned short*)(w8 + 1 * HB);
    unsigned short* p2b = (unsigned short*)(w8 + 2 * HB);
    unsigned short* Yb  = (unsigned short*)(w8 + 3 * HB);
    float*          rr  = (float*)        (w8 + 4 * HB);

    proj_kernel <<<dim3(8, 8, 3), 256, 0, stream>>>(x, Wp0, Wp1, Wp2, p0b, p1b, p2b, rr);
    attn_kernel <<<dim3(1024), 256, 0, stream>>>(p0b, p1b, p2b, rr, Wv0, Wv1, Yb);
    outmm_kernel<<<dim3(8, 8), 256, 0, stream>>>(Yb, Wc, out);
}

// Round 7
// 117.991 us; speedup vs baseline: 1.0626x; 1.0626x over previous
//
#include <hip/hip_runtime.h>
#include <hip/hip_bf16.h>
#include <math.h>

#define B 4
#define T 128
#define C 512
#define NH 8
#define HS 64
#define BH (B*NH)   // 32

typedef __attribute__((ext_vector_type(8))) short bf16x8;
typedef __attribute__((ext_vector_type(4))) float f32x4;

__device__ __forceinline__ unsigned short bfc(float x) {
    return __builtin_bit_cast(unsigned short, __float2bfloat16(x));
}
__device__ __forceinline__ unsigned int pk_bf16(float a, float b) {
    return (unsigned int)bfc(a) | ((unsigned int)bfc(b) << 16);
}
__device__ __forceinline__ float lo_f(unsigned int g) {
    return __builtin_bit_cast(float, g << 16);
}
__device__ __forceinline__ float hi_f(unsigned int g) {
    return __builtin_bit_cast(float, g & 0xffff0000u);
}

// ---------------- K1: p{0,1,2} = X @ Wp{0,1,2}  (fp32 in, bf16 out, on-the-fly cvt+transpose)
// z==2 additionally emits rr = rowsums(p2).
__global__ __launch_bounds__(256) void proj_kernel(
    const float* __restrict__ X,
    const float* __restrict__ Wp0, const float* __restrict__ Wp1, const float* __restrict__ Wp2,
    unsigned short* __restrict__ p0b, unsigned short* __restrict__ p1b,
    unsigned short* __restrict__ p2b, float* __restrict__ rr)
{
    __shared__ __align__(16) unsigned short As[64][72];
    __shared__ __align__(16) unsigned short Bs[64][72];
    __shared__ float Ls[64][69];
    __shared__ float sRS[4][64];
    const int z = blockIdx.z;
    const float* W = (z == 0) ? Wp0 : (z == 1) ? Wp1 : Wp2;
    const int m0 = blockIdx.y * 64, n0 = blockIdx.x * 64;
    const int tid = threadIdx.x;
    const int w = tid >> 6, lane = tid & 63, quad = lane >> 4, l16 = lane & 15;
    f32x4 acc[4];
    #pragma unroll
    for (int mt = 0; mt < 4; ++mt) acc[mt] = (f32x4){0.f, 0.f, 0.f, 0.f};

    for (int k0 = 0; k0 < 512; k0 += 64) {
        __syncthreads();
        #pragma unroll
        for (int it = 0; it < 2; ++it) {
            const int q = tid + it * 256;
            const int row = q >> 3, c8 = (q & 7) * 8;
            const float4 a = *(const float4*)&X[(size_t)(m0 + row) * 512 + k0 + c8];
            const float4 b = *(const float4*)&X[(size_t)(m0 + row) * 512 + k0 + c8 + 4];
            uint4 o;
            o.x = pk_bf16(a.x, a.y);
            o.y = pk_bf16(a.z, a.w);
            o.z = pk_bf16(b.x, b.y);
            o.w = pk_bf16(b.z, b.w);
            *(uint4*)&As[row][c8] = o;
        }
        #pragma unroll
        for (int it = 0; it < 4; ++it) {
            const int q = tid + it * 256;
            const int row = q >> 4, c4 = (q & 15) * 4;
            const float4 v = *(const float4*)&W[(size_t)(k0 + row) * 512 + n0 + c4];
            Ls[row][c4 + 0] = v.x; Ls[row][c4 + 1] = v.y;
            Ls[row][c4 + 2] = v.z; Ls[row][c4 + 3] = v.w;
        }
        __syncthreads();
        #pragma unroll
        for (int it = 0; it < 2; ++it) {
            const int q = tid + it * 256;
            const int nrow = q >> 3, k8 = (q & 7) * 8;
            uint4 o;
            o.x = pk_bf16(Ls[k8 + 0][nrow], Ls[k8 + 1][nrow]);
            o.y = pk_bf16(Ls[k8 + 2][nrow], Ls[k8 + 3][nrow]);
            o.z = pk_bf16(Ls[k8 + 4][nrow], Ls[k8 + 5][nrow]);
            o.w = pk_bf16(Ls[k8 + 6][nrow], Ls[k8 + 7][nrow]);
            *(uint4*)&Bs[nrow][k8] = o;
        }
        __syncthreads();
        #pragma unroll
        for (int kt = 0; kt < 2; ++kt) {
            const bf16x8 b8 = *(const bf16x8*)&Bs[w * 16 + l16][kt * 32 + quad * 8];
            #pragma unroll
            for (int mt = 0; mt < 4; ++mt) {
                const bf16x8 a8 = *(const bf16x8*)&As[mt * 16 + l16][kt * 32 + quad * 8];
                acc[mt] = __builtin_amdgcn_mfma_f32_16x16x32_bf16(a8, b8, acc[mt], 0, 0, 0);
            }
        }
    }

    {
        const int n = n0 + w * 16 + l16;
        const int h = n >> 6, d = n & 63;
        unsigned short* pz = (z == 0) ? p0b : (z == 1) ? p1b : p2b;
        #pragma unroll
        for (int mt = 0; mt < 4; ++mt) {
            #pragma unroll
            for (int r = 0; r < 4; ++r) {
                const int m = m0 + mt * 16 + quad * 4 + r;
                const int bb = m >> 7, t = m & 127;
                pz[((size_t)(bb * NH + h) * T + t) * HS + d] = bfc(acc[mt][r]);
            }
        }
    }
    if (z == 2) {
        #pragma unroll
        for (int mt = 0; mt < 4; ++mt)
            #pragma unroll
            for (int r = 0; r < 4; ++r) {
                float v = acc[mt][r];
                v += __shfl_xor(v, 1, 64); v += __shfl_xor(v, 2, 64);
                v += __shfl_xor(v, 4, 64); v += __shfl_xor(v, 8, 64);
                if (l16 == 0) sRS[w][mt * 16 + quad * 4 + r] = v;
            }
        __syncthreads();
        if (tid < 64) {
            const float s = sRS[0][tid] + sRS[1][tid] + sRS[2][tid] + sRS[3][tid];
            const int m = m0 + tid, bb = m >> 7, tl = m & 127, h = n0 >> 6;
            rr[(bb * NH + h) * T + tl] = s;
        }
    }
}

// ---------------- K2: attention; 512 blocks = (bh, ig 0..15) x 8 i's
// double-buffered full-width E -> 1 barrier per i; global-mhat + rk hoisted.
__global__ __launch_bounds__(256) void attn_kernel(
    const unsigned short* __restrict__ p0b, const unsigned short* __restrict__ p1b,
    const unsigned short* __restrict__ p2b, const float* __restrict__ rr,
    const float* __restrict__ Wv0, const float* __restrict__ Wv1,
    unsigned short* __restrict__ Yb)
{
    __shared__ __align__(16) union {
        struct {
            unsigned short sWv[64][72];      // Wv^T bf16 [d][k] (one at a time)
            unsigned short sVst[64][136];    // V^T staging [d][t] (V0 then V1)
        } v;                                  // 26.6 KB
        unsigned short sE[2][128 * 128];     // double-buffered full-width E; 64 KB
    } u;
    __shared__ float sS[8][128];
    __shared__ float srr[128];
    __shared__ float sZ[2][4];

    const int bid = blockIdx.x;
    const int bh = bid & (BH - 1);
    const int ig = bid >> 5;                 // 0..15
    const int tid = threadIdx.x;
    const int w = tid >> 6;
    const int lane = tid & 63;
    const int quad = lane >> 4;
    const int l16 = lane & 15;

    if (tid < 128) srr[tid] = rr[bh * T + tid];

    // ---- stage Wv0^T ----
    #pragma unroll
    for (int it = 0; it < 4; ++it) {
        const int k = (tid >> 4) + it * 16;
        const int d0 = (tid & 15) * 4;
        const float4 wv = *(const float4*)&Wv0[(size_t)k * 64 + d0];
        u.v.sWv[d0 + 0][k] = bfc(wv.x); u.v.sWv[d0 + 1][k] = bfc(wv.y);
        u.v.sWv[d0 + 2][k] = bfc(wv.z); u.v.sWv[d0 + 3][k] = bfc(wv.w);
    }
    __syncthreads();                                       // bar1: sWv(Wv0) + srr

    // ---- V0 = p1 @ Wv0 -> sVst ----
    #pragma unroll
    for (int nn = 0; nn < 2; ++nn) {
        const int nt = w + nn * 4;
        f32x4 vacc[4];
        #pragma unroll
        for (int mt = 0; mt < 4; ++mt) vacc[mt] = (f32x4){0.f, 0.f, 0.f, 0.f};
        #pragma unroll
        for (int kt = 0; kt < 2; ++kt) {
            const bf16x8 b8 = *(const bf16x8*)&p1b[((size_t)bh * T + nt * 16 + l16) * HS + kt * 32 + quad * 8];
            #pragma unroll
            for (int mt = 0; mt < 4; ++mt) {
                const bf16x8 a8 = *(const bf16x8*)&u.v.sWv[mt * 16 + l16][kt * 32 + quad * 8];
                vacc[mt] = __builtin_amdgcn_mfma_f32_16x16x32_bf16(a8, b8, vacc[mt], 0, 0, 0);
            }
        }
        #pragma unroll
        for (int mt = 0; mt < 4; ++mt)
            #pragma unroll
            for (int r = 0; r < 4; ++r)
                u.v.sVst[mt * 16 + quad * 4 + r][nt * 16 + l16] = bfc(vacc[mt][r]);
    }
    __syncthreads();                                       // bar2: sVst(V0)

    // ---- v0 regs + stage Wv1^T ----
    uint2 v0r[8];
    #pragma unroll
    for (int mt = 0; mt < 8; ++mt)
        v0r[mt] = *(const uint2*)&u.v.sVst[(w << 4) + l16][(mt << 4) + (quad << 2)];
    #pragma unroll
    for (int it = 0; it < 4; ++it) {
        const int k = (tid >> 4) + it * 16;
        const int d0 = (tid & 15) * 4;
        const float4 wv = *(const float4*)&Wv1[(size_t)k * 64 + d0];
        u.v.sWv[d0 + 0][k] = bfc(wv.x); u.v.sWv[d0 + 1][k] = bfc(wv.y);
        u.v.sWv[d0 + 2][k] = bfc(wv.z); u.v.sWv[d0 + 3][k] = bfc(wv.w);
    }
    __syncthreads();                                       // bar3: v0r read + sWv(Wv1)

    // ---- V1 = p2 @ Wv1 -> sVst ----
    #pragma unroll
    for (int nn = 0; nn < 2; ++nn) {
        const int nt = w + nn * 4;
        f32x4 vacc[4];
        #pragma unroll
        for (int mt = 0; mt < 4; ++mt) vacc[mt] = (f32x4){0.f, 0.f, 0.f, 0.f};
        #pragma unroll
        for (int kt = 0; kt < 2; ++kt) {
            const bf16x8 b8 = *(const bf16x8*)&p2b[((size_t)bh * T + nt * 16 + l16) * HS + kt * 32 + quad * 8];
            #pragma unroll
            for (int mt = 0; mt < 4; ++mt) {
                const bf16x8 a8 = *(const bf16x8*)&u.v.sWv[mt * 16 + l16][kt * 32 + quad * 8];
                vacc[mt] = __builtin_amdgcn_mfma_f32_16x16x32_bf16(a8, b8, vacc[mt], 0, 0, 0);
            }
        }
        #pragma unroll
        for (int mt = 0; mt < 4; ++mt)
            #pragma unroll
            for (int r = 0; r < 4; ++r)
                u.v.sVst[mt * 16 + quad * 4 + r][nt * 16 + l16] = bfc(vacc[mt][r]);
    }
    __syncthreads();                                       // bar4: sVst(V1)

    // ---- v1 regs + all 8 S rows in one MFMA pass (A rows 0..7 = p0[i_q]) ----
    uint4 v1r[4];
    #pragma unroll
    for (int kt = 0; kt < 4; ++kt)
        v1r[kt] = *(const uint4*)&u.v.sVst[(w << 4) + l16][(quad << 3) + (kt << 5)];
    {
        const int qr = l16 & 7;
        const int irow = (qr & 1) ? (16 * qr + 15 - ig) : (16 * qr + ig);
        const unsigned short* ap = p0b + ((size_t)bh * T + irow) * HS + (quad << 3);
        const unsigned short* bp = p1b + (size_t)bh * T * HS + (quad << 3);
        f32x4 s0 = (f32x4){0.f, 0.f, 0.f, 0.f};
        f32x4 s1 = (f32x4){0.f, 0.f, 0.f, 0.f};
        #pragma unroll
        for (int kt = 0; kt < 2; ++kt) {
            const bf16x8 a8 = *(const bf16x8*)(ap + (kt << 5));
            const bf16x8 b0 = *(const bf16x8*)(bp + (size_t)((w << 5) + l16) * HS + (kt << 5));
            const bf16x8 b1 = *(const bf16x8*)(bp + (size_t)((w << 5) + 16 + l16) * HS + (kt << 5));
            s0 = __builtin_amdgcn_mfma_f32_16x16x32_bf16(a8, b0, s0, 0, 0, 0);
            s1 = __builtin_amdgcn_mfma_f32_16x16x32_bf16(a8, b1, s1, 0, 0, 0);
        }
        if (quad < 2) {
            #pragma unroll
            for (int r = 0; r < 4; ++r) {
                sS[quad * 4 + r][(w << 5) + l16]      = s0[r] * 0.125f;
                sS[quad * 4 + r][(w << 5) + 16 + l16] = s1[r] * 0.125f;
            }
        }
    }
    __syncthreads();                                       // bar5: sS ready; v1r read; sE usable

    const float L2E = 1.4426950408889634f;

    // ---- hoisted: global mhat (upper bound, shift-invariance) + rk + bexp ----
    float mhat;
    {
        float aS = 0.f;
        #pragma unroll
        for (int q = 0; q < 8; ++q) {
            aS = fmaxf(aS, fabsf(sS[q][lane]));
            aS = fmaxf(aS, fabsf(sS[q][64 + lane]));
        }
        float aR = fmaxf(fabsf(srr[lane]), fabsf(srr[64 + lane]));
        #pragma unroll
        for (int off = 32; off; off >>= 1) {
            aS = fmaxf(aS, __shfl_xor(aS, off, 64));
            aR = fmaxf(aR, __shfl_xor(aR, off, 64));
        }
        mhat = aS * aR;
    }
    const float bexp = -mhat * L2E;
    const int cc = tid & 15;           // 16B chunk (8 bf16 cols) of the 128-col row
    const int rowin = tid >> 4;        // row within 16-row pass
    const int k0l = cc << 3;
    float rk[8];
    *(float4*)&rk[0] = *(const float4*)&srr[k0l];
    *(float4*)&rk[4] = *(const float4*)&srr[k0l + 4];

    for (int qq = 7; qq >= 0; --qq) {                      // biggest i first
        const int i = (qq & 1) ? (16 * qq + 15 - ig) : (16 * qq + ig);
        const float* sSq = sS[qq];
        const int mtmax = i >> 4;
        const int buf = qq & 1;
        float zacc = 0.f;

        // ---- full-width E build into buf (other buf may still be MFMA-read) ----
        const int npass = mtmax + 1;
        for (int p = 0; p < npass; ++p) {
            const int jj = (p << 4) + rowin;
            uint4 o = {0u, 0u, 0u, 0u};
            if (jj <= i && k0l <= jj) {
                const float aL = sSq[jj] * L2E;
                const int dlim = jj - k0l;
                float e[8];
                #pragma unroll
                for (int q = 0; q < 8; ++q) {
                    const float ex = __builtin_amdgcn_exp2f(fmaf(aL, rk[q], bexp));
                    e[q] = (q <= dlim) ? ex : 0.f;
                    zacc += e[q];
                }
                o.x = pk_bf16(e[0], e[1]);
                o.y = pk_bf16(e[2], e[3]);
                o.z = pk_bf16(e[4], e[5]);
                o.w = pk_bf16(e[6], e[7]);
            }
            *(uint4*)&u.sE[buf][(jj << 7) + ((cc ^ (jj & 7)) << 3)] = o;
        }
        #pragma unroll
        for (int off = 32; off; off >>= 1) zacc += __shfl_xor(zacc, off, 64);
        if (lane == 0) sZ[buf][w] = zacc;
        __syncthreads();                                   // E[buf] + Z[buf] ready; prev MFMA drained

        // ---- PV MFMA from buf ----
        f32x4 acc[8];
        #pragma unroll
        for (int mt = 0; mt < 8; ++mt) acc[mt] = (f32x4){0.f, 0.f, 0.f, 0.f};
        #pragma unroll
        for (int mt = 0; mt < 8; ++mt) {
            if (mt <= mtmax) {
                #pragma unroll
                for (int kt = 0; kt < 4; ++kt) {
                    if (kt <= (mt >> 1)) {
                        const int ch = ((kt << 2) + quad) ^ (l16 & 7);
                        const bf16x8 a8 = *(const bf16x8*)&u.sE[buf][(((mt << 4) + l16) << 7) + (ch << 3)];
                        acc[mt] = __builtin_amdgcn_mfma_f32_16x16x32_bf16(
                            a8, __builtin_bit_cast(bf16x8, v1r[kt]), acc[mt], 0, 0, 0);
                    }
                }
            }
        }
        const float Z = sZ[buf][0] + sZ[buf][1] + sZ[buf][2] + sZ[buf][3];

        // ---- epilogue: y[d] = sum_j V0[j][d]*Tmat[j][d] / Z ; V0 in regs ----
        float part = 0.f;
        #pragma unroll
        for (int mt = 0; mt < 8; ++mt) {
            if (mt < mtmax) {
                const uint2 uu = v0r[mt];
                part = fmaf(lo_f(uu.x), acc[mt][0], part);
                part = fmaf(hi_f(uu.x), acc[mt][1], part);
                part = fmaf(lo_f(uu.y), acc[mt][2], part);
                part = fmaf(hi_f(uu.y), acc[mt][3], part);
            } else if (mt == mtmax) {
                const uint2 uu = v0r[mt];
                const int jb = (mt << 4) + (quad << 2);
                if (jb + 0 <= i) part = fmaf(lo_f(uu.x), acc[mt][0], part);
                if (jb + 1 <= i) part = fmaf(hi_f(uu.x), acc[mt][1], part);
                if (jb + 2 <= i) part = fmaf(lo_f(uu.y), acc[mt][2], part);
                if (jb + 3 <= i) part = fmaf(hi_f(uu.y), acc[mt][3], part);
            }
        }
        part += __shfl_xor(part, 16, 64);
        part += __shfl_xor(part, 32, 64);
        if (lane < 16) {
            const int bb = bh >> 3, hh = bh & 7;
            Yb[((size_t)(bb * T + i) * C) + hh * HS + (w << 4) + l16] = bfc(part / Z);
        }
        // no trailing barrier: next build targets the other buffer.
    }
}

// ---------------- K3: OUT = Yb @ Wc (bf16 A, fp32 W transposed on the fly, fp32 out)
__global__ __launch_bounds__(256) void outmm_kernel(
    const unsigned short* __restrict__ Ab, const float* __restrict__ Wc,
    float* __restrict__ OUT)
{
    __shared__ __align__(16) unsigned short As[64][72];
    __shared__ __align__(16) unsigned short Bs[64][72];
    __shared__ float Ls[64][69];
    const int m0 = blockIdx.y * 64, n0 = blockIdx.x * 64;
    const int tid = threadIdx.x;
    const int w = tid >> 6, lane = tid & 63, quad = lane >> 4, l16 = lane & 15;
    f32x4 acc[4];
    #pragma unroll
    for (int mt = 0; mt < 4; ++mt) acc[mt] = (f32x4){0.f, 0.f, 0.f, 0.f};
    for (int k0 = 0; k0 < 512; k0 += 64) {
        __syncthreads();
        #pragma unroll
        for (int it = 0; it < 2; ++it) {
            const int q = tid + it * 256;
            const int row = q >> 3, c8 = (q & 7) * 8;
            *(uint4*)&As[row][c8] = *(const uint4*)&Ab[(size_t)(m0 + row) * 512 + k0 + c8];
        }
        #pragma unroll
        for (int it = 0; it < 4; ++it) {
            const int q = tid + it * 256;
            const int row = q >> 4, c4 = (q & 15) * 4;
            const float4 v = *(const float4*)&Wc[(size_t)(k0 + row) * 512 + n0 + c4];
            Ls[row][c4 + 0] = v.x; Ls[row][c4 + 1] = v.y;
            Ls[row][c4 + 2] = v.z; Ls[row][c4 + 3] = v.w;
        }
        __syncthreads();
        #pragma unroll
        for (int it = 0; it < 2; ++it) {
            const int q = tid + it * 256;
            const int nrow = q >> 3, k8 = (q & 7) * 8;
            uint4 o;
            o.x = pk_bf16(Ls[k8 + 0][nrow], Ls[k8 + 1][nrow]);
            o.y = pk_bf16(Ls[k8 + 2][nrow], Ls[k8 + 3][nrow]);
            o.z = pk_bf16(Ls[k8 + 4][nrow], Ls[k8 + 5][nrow]);
            o.w = pk_bf16(Ls[k8 + 6][nrow], Ls[k8 + 7][nrow]);
            *(uint4*)&Bs[nrow][k8] = o;
        }
        __syncthreads();
        #pragma unroll
        for (int kt = 0; kt < 2; ++kt) {
            const bf16x8 b8 = *(const bf16x8*)&Bs[w * 16 + l16][kt * 32 + quad * 8];
            #pragma unroll
            for (int mt = 0; mt < 4; ++mt) {
                const bf16x8 a8 = *(const bf16x8*)&As[mt * 16 + l16][kt * 32 + quad * 8];
                acc[mt] = __builtin_amdgcn_mfma_f32_16x16x32_bf16(a8, b8, acc[mt], 0, 0, 0);
            }
        }
    }
    const int n = n0 + w * 16 + l16;
    #pragma unroll
    for (int mt = 0; mt < 4; ++mt)
        #pragma unroll
        for (int r = 0; r < 4; ++r) {
            const int mrow = m0 + mt * 16 + quad * 4 + r;
            OUT[(size_t)mrow * 512 + n] = acc[mt][r];
        }
}

extern "C" void kernel_launch(void* const* d_in, const int* in_sizes, int n_in,
                              void* d_out, int out_size, void* d_ws, size_t ws_size,
                              hipStream_t stream)
{
    const float* x   = (const float*)d_in[0];
    const float* Wp0 = (const float*)d_in[1];
    const float* Wp1 = (const float*)d_in[2];
    const float* Wp2 = (const float*)d_in[3];
    const float* Wv0 = (const float*)d_in[4];
    const float* Wv1 = (const float*)d_in[5];
    const float* Wc  = (const float*)d_in[6];
    float* out = (float*)d_out;

    char* w8 = (char*)d_ws;
    const size_t HB = 512 * 1024;
    unsigned short* p0b = (unsigned short*)(w8 + 0 * HB);
    unsigned short* p1b = (unsigned short*)(w8 + 1 * HB);
    unsigned short* p2b = (unsigned short*)(w8 + 2 * HB);
    unsigned short* Yb  = (unsigned short*)(w8 + 3 * HB);
    float*          rr  = (float*)        (w8 + 4 * HB);

    proj_kernel <<<dim3(8, 8, 3), 256, 0, stream>>>(x, Wp0, Wp1, Wp2, p0b, p1b, p2b, rr);
    attn_kernel <<<dim3(512), 256, 0, stream>>>(p0b, p1b, p2b, rr, Wv0, Wv1, Yb);
    outmm_kernel<<<dim3(8, 8), 256, 0, stream>>>(Yb, Wc, out);
}

// Round 8
// 113.827 us; speedup vs baseline: 1.1015x; 1.0366x over previous
//
#include <hip/hip_runtime.h>
#include <hip/hip_bf16.h>
#include <math.h>

#define B 4
#define T 128
#define C 512
#define NH 8
#define HS 64
#define BH (B*NH)   // 32

typedef __attribute__((ext_vector_type(8))) short bf16x8;
typedef __attribute__((ext_vector_type(4))) float f32x4;

__device__ __forceinline__ unsigned short bfc(float x) {
    return __builtin_bit_cast(unsigned short, __float2bfloat16(x));
}
__device__ __forceinline__ unsigned int pk_bf16(float a, float b) {
    return (unsigned int)bfc(a) | ((unsigned int)bfc(b) << 16);
}
__device__ __forceinline__ float lo_f(unsigned int g) {
    return __builtin_bit_cast(float, g << 16);
}
__device__ __forceinline__ float hi_f(unsigned int g) {
    return __builtin_bit_cast(float, g & 0xffff0000u);
}

// ---------------- K1: p{0,1,2} = X @ Wp{0,1,2}  (fp32 in, bf16 out, on-the-fly cvt+transpose)
// z==2 additionally emits rr = rowsums(p2).
__global__ __launch_bounds__(256) void proj_kernel(
    const float* __restrict__ X,
    const float* __restrict__ Wp0, const float* __restrict__ Wp1, const float* __restrict__ Wp2,
    unsigned short* __restrict__ p0b, unsigned short* __restrict__ p1b,
    unsigned short* __restrict__ p2b, float* __restrict__ rr)
{
    __shared__ __align__(16) unsigned short As[64][72];
    __shared__ __align__(16) unsigned short Bs[64][72];
    __shared__ float Ls[64][69];
    __shared__ float sRS[4][64];
    const int z = blockIdx.z;
    const float* W = (z == 0) ? Wp0 : (z == 1) ? Wp1 : Wp2;
    const int m0 = blockIdx.y * 64, n0 = blockIdx.x * 64;
    const int tid = threadIdx.x;
    const int w = tid >> 6, lane = tid & 63, quad = lane >> 4, l16 = lane & 15;
    f32x4 acc[4];
    #pragma unroll
    for (int mt = 0; mt < 4; ++mt) acc[mt] = (f32x4){0.f, 0.f, 0.f, 0.f};

    for (int k0 = 0; k0 < 512; k0 += 64) {
        __syncthreads();
        #pragma unroll
        for (int it = 0; it < 2; ++it) {
            const int q = tid + it * 256;
            const int row = q >> 3, c8 = (q & 7) * 8;
            const float4 a = *(const float4*)&X[(size_t)(m0 + row) * 512 + k0 + c8];
            const float4 b = *(const float4*)&X[(size_t)(m0 + row) * 512 + k0 + c8 + 4];
            uint4 o;
            o.x = pk_bf16(a.x, a.y);
            o.y = pk_bf16(a.z, a.w);
            o.z = pk_bf16(b.x, b.y);
            o.w = pk_bf16(b.z, b.w);
            *(uint4*)&As[row][c8] = o;
        }
        #pragma unroll
        for (int it = 0; it < 4; ++it) {
            const int q = tid + it * 256;
            const int row = q >> 4, c4 = (q & 15) * 4;
            const float4 v = *(const float4*)&W[(size_t)(k0 + row) * 512 + n0 + c4];
            Ls[row][c4 + 0] = v.x; Ls[row][c4 + 1] = v.y;
            Ls[row][c4 + 2] = v.z; Ls[row][c4 + 3] = v.w;
        }
        __syncthreads();
        #pragma unroll
        for (int it = 0; it < 2; ++it) {
            const int q = tid + it * 256;
            const int nrow = q >> 3, k8 = (q & 7) * 8;
            uint4 o;
            o.x = pk_bf16(Ls[k8 + 0][nrow], Ls[k8 + 1][nrow]);
            o.y = pk_bf16(Ls[k8 + 2][nrow], Ls[k8 + 3][nrow]);
            o.z = pk_bf16(Ls[k8 + 4][nrow], Ls[k8 + 5][nrow]);
            o.w = pk_bf16(Ls[k8 + 6][nrow], Ls[k8 + 7][nrow]);
            *(uint4*)&Bs[nrow][k8] = o;
        }
        __syncthreads();
        #pragma unroll
        for (int kt = 0; kt < 2; ++kt) {
            const bf16x8 b8 = *(const bf16x8*)&Bs[w * 16 + l16][kt * 32 + quad * 8];
            #pragma unroll
            for (int mt = 0; mt < 4; ++mt) {
                const bf16x8 a8 = *(const bf16x8*)&As[mt * 16 + l16][kt * 32 + quad * 8];
                acc[mt] = __builtin_amdgcn_mfma_f32_16x16x32_bf16(a8, b8, acc[mt], 0, 0, 0);
            }
        }
    }

    {
        const int n = n0 + w * 16 + l16;
        const int h = n >> 6, d = n & 63;
        unsigned short* pz = (z == 0) ? p0b : (z == 1) ? p1b : p2b;
        #pragma unroll
        for (int mt = 0; mt < 4; ++mt) {
            #pragma unroll
            for (int r = 0; r < 4; ++r) {
                const int m = m0 + mt * 16 + quad * 4 + r;
                const int bb = m >> 7, t = m & 127;
                pz[((size_t)(bb * NH + h) * T + t) * HS + d] = bfc(acc[mt][r]);
            }
        }
    }
    if (z == 2) {
        #pragma unroll
        for (int mt = 0; mt < 4; ++mt)
            #pragma unroll
            for (int r = 0; r < 4; ++r) {
                float v = acc[mt][r];
                v += __shfl_xor(v, 1, 64); v += __shfl_xor(v, 2, 64);
                v += __shfl_xor(v, 4, 64); v += __shfl_xor(v, 8, 64);
                if (l16 == 0) sRS[w][mt * 16 + quad * 4 + r] = v;
            }
        __syncthreads();
        if (tid < 64) {
            const float s = sRS[0][tid] + sRS[1][tid] + sRS[2][tid] + sRS[3][tid];
            const int m = m0 + tid, bb = m >> 7, tl = m & 127, h = n0 >> 6;
            rr[(bb * NH + h) * T + tl] = s;
        }
    }
}

// ---------------- K2: attention; 512 blocks x 512 threads (8 waves); (bh, ig 0..15) x 8 i's
// double-buffered full-width E, 1 barrier/i; PV split across wave pairs; divide deferred.
__global__ __launch_bounds__(512, 4) void attn_kernel(
    const unsigned short* __restrict__ p0b, const unsigned short* __restrict__ p1b,
    const unsigned short* __restrict__ p2b, const float* __restrict__ rr,
    const float* __restrict__ Wv0, const float* __restrict__ Wv1,
    unsigned short* __restrict__ Yb)
{
    __shared__ __align__(16) union {
        struct {
            unsigned short sWv[64][72];      // Wv^T bf16 [d][k] (one at a time)
            unsigned short sVst[64][136];    // V^T staging [d][t] (V0 then V1)
        } v;                                  // 26.6 KB
        unsigned short sE[2][128 * 128];     // double-buffered full-width E; 64 KB
    } u;
    __shared__ float sS[8][128];
    __shared__ float srr[128];
    __shared__ float sZarr[8][8];            // [qq][wave] Z partials
    __shared__ float sY[8][2][64];           // [qq][mt-half][d] y partials (pre-divide)

    const int bid = blockIdx.x;
    const int bh = bid & (BH - 1);
    const int ig = bid >> 5;                 // 0..15
    const int tid = threadIdx.x;
    const int w = tid >> 6;                  // 0..7
    const int lane = tid & 63;
    const int quad = lane >> 4;
    const int l16 = lane & 15;
    const int wq = w & 3;                    // d-slice group (d = wq*16+l16)
    const int h4 = (w >> 2) * 4;             // mt base: waves 0-3 -> 0, waves 4-7 -> 4

    if (tid < 128) srr[tid] = rr[bh * T + tid];

    // ---- stage Wv0^T ----
    #pragma unroll
    for (int it = 0; it < 2; ++it) {
        const int k = (tid >> 4) + it * 32;
        const int d0 = (tid & 15) * 4;
        const float4 wv = *(const float4*)&Wv0[(size_t)k * 64 + d0];
        u.v.sWv[d0 + 0][k] = bfc(wv.x); u.v.sWv[d0 + 1][k] = bfc(wv.y);
        u.v.sWv[d0 + 2][k] = bfc(wv.z); u.v.sWv[d0 + 3][k] = bfc(wv.w);
    }
    __syncthreads();                                       // bar1: sWv(Wv0) + srr

    // ---- V0 = p1 @ Wv0 -> sVst (wave w covers nt = w) ----
    {
        f32x4 vacc[4];
        #pragma unroll
        for (int mt = 0; mt < 4; ++mt) vacc[mt] = (f32x4){0.f, 0.f, 0.f, 0.f};
        #pragma unroll
        for (int kt = 0; kt < 2; ++kt) {
            const bf16x8 b8 = *(const bf16x8*)&p1b[((size_t)bh * T + w * 16 + l16) * HS + kt * 32 + quad * 8];
            #pragma unroll
            for (int mt = 0; mt < 4; ++mt) {
                const bf16x8 a8 = *(const bf16x8*)&u.v.sWv[mt * 16 + l16][kt * 32 + quad * 8];
                vacc[mt] = __builtin_amdgcn_mfma_f32_16x16x32_bf16(a8, b8, vacc[mt], 0, 0, 0);
            }
        }
        #pragma unroll
        for (int mt = 0; mt < 4; ++mt)
            #pragma unroll
            for (int r = 0; r < 4; ++r)
                u.v.sVst[mt * 16 + quad * 4 + r][w * 16 + l16] = bfc(vacc[mt][r]);
    }
    __syncthreads();                                       // bar2: sVst(V0)

    // ---- v0 regs (this wave's mt-half of its d-slice) + stage Wv1^T ----
    uint2 v0r[4];
    #pragma unroll
    for (int m = 0; m < 4; ++m)
        v0r[m] = *(const uint2*)&u.v.sVst[(wq << 4) + l16][((h4 + m) << 4) + (quad << 2)];
    #pragma unroll
    for (int it = 0; it < 2; ++it) {
        const int k = (tid >> 4) + it * 32;
        const int d0 = (tid & 15) * 4;
        const float4 wv = *(const float4*)&Wv1[(size_t)k * 64 + d0];
        u.v.sWv[d0 + 0][k] = bfc(wv.x); u.v.sWv[d0 + 1][k] = bfc(wv.y);
        u.v.sWv[d0 + 2][k] = bfc(wv.z); u.v.sWv[d0 + 3][k] = bfc(wv.w);
    }
    __syncthreads();                                       // bar3: v0r read + sWv(Wv1)

    // ---- V1 = p2 @ Wv1 -> sVst ----
    {
        f32x4 vacc[4];
        #pragma unroll
        for (int mt = 0; mt < 4; ++mt) vacc[mt] = (f32x4){0.f, 0.f, 0.f, 0.f};
        #pragma unroll
        for (int kt = 0; kt < 2; ++kt) {
            const bf16x8 b8 = *(const bf16x8*)&p2b[((size_t)bh * T + w * 16 + l16) * HS + kt * 32 + quad * 8];
            #pragma unroll
            for (int mt = 0; mt < 4; ++mt) {
                const bf16x8 a8 = *(const bf16x8*)&u.v.sWv[mt * 16 + l16][kt * 32 + quad * 8];
                vacc[mt] = __builtin_amdgcn_mfma_f32_16x16x32_bf16(a8, b8, vacc[mt], 0, 0, 0);
            }
        }
        #pragma unroll
        for (int mt = 0; mt < 4; ++mt)
            #pragma unroll
            for (int r = 0; r < 4; ++r)
                u.v.sVst[mt * 16 + quad * 4 + r][w * 16 + l16] = bfc(vacc[mt][r]);
    }
    __syncthreads();                                       // bar4: sVst(V1)

    // ---- v1 regs + all 8 S rows (wave w covers j = w*16+l16) ----
    uint4 v1r[4];
    #pragma unroll
    for (int kt = 0; kt < 4; ++kt)
        v1r[kt] = *(const uint4*)&u.v.sVst[(wq << 4) + l16][(quad << 3) + (kt << 5)];
    {
        const int qr = l16 & 7;
        const int irow = (qr & 1) ? (16 * qr + 15 - ig) : (16 * qr + ig);
        const unsigned short* ap = p0b + ((size_t)bh * T + irow) * HS + (quad << 3);
        const unsigned short* bp = p1b + (size_t)bh * T * HS + (quad << 3);
        f32x4 s0 = (f32x4){0.f, 0.f, 0.f, 0.f};
        #pragma unroll
        for (int kt = 0; kt < 2; ++kt) {
            const bf16x8 a8 = *(const bf16x8*)(ap + (kt << 5));
            const bf16x8 b0 = *(const bf16x8*)(bp + (size_t)((w << 4) + l16) * HS + (kt << 5));
            s0 = __builtin_amdgcn_mfma_f32_16x16x32_bf16(a8, b0, s0, 0, 0, 0);
        }
        if (quad < 2) {
            #pragma unroll
            for (int r = 0; r < 4; ++r)
                sS[quad * 4 + r][(w << 4) + l16] = s0[r] * 0.125f;
        }
    }
    __syncthreads();                                       // bar5: sS ready; v1r read; sE usable

    const float L2E = 1.4426950408889634f;

    // ---- hoisted: global mhat (upper bound via shift-invariance) + rk + bexp ----
    float mhat;
    {
        float aS = 0.f;
        #pragma unroll
        for (int q = 0; q < 8; ++q) {
            aS = fmaxf(aS, fabsf(sS[q][lane]));
            aS = fmaxf(aS, fabsf(sS[q][64 + lane]));
        }
        float aR = fmaxf(fabsf(srr[lane]), fabsf(srr[64 + lane]));
        #pragma unroll
        for (int off = 32; off; off >>= 1) {
            aS = fmaxf(aS, __shfl_xor(aS, off, 64));
            aR = fmaxf(aR, __shfl_xor(aR, off, 64));
        }
        mhat = aS * aR;
    }
    const float bexp = -mhat * L2E;
    const int cc = tid & 15;           // 16B chunk (8 bf16 cols) of the 128-col row
    const int rowin = tid >> 4;        // row within 32-row pass (0..31)
    const int k0l = cc << 3;
    float rk[8];
    *(float4*)&rk[0] = *(const float4*)&srr[k0l];
    *(float4*)&rk[4] = *(const float4*)&srr[k0l + 4];

    for (int qq = 7; qq >= 0; --qq) {                      // biggest i first
        const int i = (qq & 1) ? (16 * qq + 15 - ig) : (16 * qq + ig);
        const float* sSq = sS[qq];
        const int mtmax = i >> 4;
        const int buf = qq & 1;
        float zacc = 0.f;

        // ---- full-width E build into buf (32 rows/pass) ----
        const int npass = (mtmax + 2) >> 1;
        for (int p = 0; p < npass; ++p) {
            const int jj = (p << 5) + rowin;
            uint4 o = {0u, 0u, 0u, 0u};
            if (jj <= i && k0l <= jj) {
                const float aL = sSq[jj] * L2E;
                const int dlim = jj - k0l;
                float e[8];
                #pragma unroll
                for (int q = 0; q < 8; ++q) {
                    const float ex = __builtin_amdgcn_exp2f(fmaf(aL, rk[q], bexp));
                    e[q] = (q <= dlim) ? ex : 0.f;
                    zacc += e[q];
                }
                o.x = pk_bf16(e[0], e[1]);
                o.y = pk_bf16(e[2], e[3]);
                o.z = pk_bf16(e[4], e[5]);
                o.w = pk_bf16(e[6], e[7]);
            }
            *(uint4*)&u.sE[buf][(jj << 7) + ((cc ^ (jj & 7)) << 3)] = o;
        }
        #pragma unroll
        for (int off = 32; off; off >>= 1) zacc += __shfl_xor(zacc, off, 64);
        if (lane == 0) sZarr[qq][w] = zacc;
        __syncthreads();                                   // E[buf] ready; prev MFMA drained

        // ---- PV MFMA from buf: wave handles its mt-half ----
        f32x4 acc[4];
        #pragma unroll
        for (int m = 0; m < 4; ++m) acc[m] = (f32x4){0.f, 0.f, 0.f, 0.f};
        #pragma unroll
        for (int mtl = 0; mtl < 4; ++mtl) {
            const int mt = h4 + mtl;
            if (mt <= mtmax) {
                #pragma unroll
                for (int kt = 0; kt < 4; ++kt) {
                    if (kt <= (mt >> 1)) {
                        const int ch = ((kt << 2) + quad) ^ (l16 & 7);
                        const bf16x8 a8 = *(const bf16x8*)&u.sE[buf][(((mt << 4) + l16) << 7) + (ch << 3)];
                        acc[mtl] = __builtin_amdgcn_mfma_f32_16x16x32_bf16(
                            a8, __builtin_bit_cast(bf16x8, v1r[kt]), acc[mtl], 0, 0, 0);
                    }
                }
            }
        }

        // ---- partial epilogue (no divide): sum over this wave's mt-half ----
        float part = 0.f;
        #pragma unroll
        for (int mtl = 0; mtl < 4; ++mtl) {
            const int mt = h4 + mtl;
            if (mt < mtmax) {
                const uint2 uu = v0r[mtl];
                part = fmaf(lo_f(uu.x), acc[mtl][0], part);
                part = fmaf(hi_f(uu.x), acc[mtl][1], part);
                part = fmaf(lo_f(uu.y), acc[mtl][2], part);
                part = fmaf(hi_f(uu.y), acc[mtl][3], part);
            } else if (mt == mtmax) {
                const uint2 uu = v0r[mtl];
                const int jb = (mt << 4) + (quad << 2);
                if (jb + 0 <= i) part = fmaf(lo_f(uu.x), acc[mtl][0], part);
                if (jb + 1 <= i) part = fmaf(hi_f(uu.x), acc[mtl][1], part);
                if (jb + 2 <= i) part = fmaf(lo_f(uu.y), acc[mtl][2], part);
                if (jb + 3 <= i) part = fmaf(hi_f(uu.y), acc[mtl][3], part);
            }
        }
        part += __shfl_xor(part, 16, 64);
        part += __shfl_xor(part, 32, 64);
        if (lane < 16) sY[qq][w >> 2][(wq << 4) + l16] = part;
        // no trailing barrier: next build targets the other buffer.
    }

    // ---- final combine + store: wave w -> qq = w, d = lane ----
    __syncthreads();
    {
        const int qq = w;
        const int d = lane;
        const int i = (qq & 1) ? (16 * qq + 15 - ig) : (16 * qq + ig);
        float Z = 0.f;
        #pragma unroll
        for (int ww = 0; ww < 8; ++ww) Z += sZarr[qq][ww];
        const float y = sY[qq][0][d] + sY[qq][1][d];
        const int bb = bh >> 3, hh = bh & 7;
        Yb[((size_t)(bb * T + i) * C) + hh * HS + d] = bfc(y / Z);
    }
}

// ---------------- K3: OUT = Yb @ Wc (bf16 A, fp32 W transposed on the fly, fp32 out)
__global__ __launch_bounds__(256) void outmm_kernel(
    const unsigned short* __restrict__ Ab, const float* __restrict__ Wc,
    float* __restrict__ OUT)
{
    __shared__ __align__(16) unsigned short As[64][72];
    __shared__ __align__(16) unsigned short Bs[64][72];
    __shared__ float Ls[64][69];
    const int m0 = blockIdx.y * 64, n0 = blockIdx.x * 64;
    const int tid = threadIdx.x;
    const int w = tid >> 6, lane = tid & 63, quad = lane >> 4, l16 = lane & 15;
    f32x4 acc[4];
    #pragma unroll
    for (int mt = 0; mt < 4; ++mt) acc[mt] = (f32x4){0.f, 0.f, 0.f, 0.f};
    for (int k0 = 0; k0 < 512; k0 += 64) {
        __syncthreads();
        #pragma unroll
        for (int it = 0; it < 2; ++it) {
            const int q = tid + it * 256;
            const int row = q >> 3, c8 = (q & 7) * 8;
            *(uint4*)&As[row][c8] = *(const uint4*)&Ab[(size_t)(m0 + row) * 512 + k0 + c8];
        }
        #pragma unroll
        for (int it = 0; it < 4; ++it) {
            const int q = tid + it * 256;
            const int row = q >> 4, c4 = (q & 15) * 4;
            const float4 v = *(const float4*)&Wc[(size_t)(k0 + row) * 512 + n0 + c4];
            Ls[row][c4 + 0] = v.x; Ls[row][c4 + 1] = v.y;
            Ls[row][c4 + 2] = v.z; Ls[row][c4 + 3] = v.w;
        }
        __syncthreads();
        #pragma unroll
        for (int it = 0; it < 2; ++it) {
            const int q = tid + it * 256;
            const int nrow = q >> 3, k8 = (q & 7) * 8;
            uint4 o;
            o.x = pk_bf16(Ls[k8 + 0][nrow], Ls[k8 + 1][nrow]);
            o.y = pk_bf16(Ls[k8 + 2][nrow], Ls[k8 + 3][nrow]);
            o.z = pk_bf16(Ls[k8 + 4][nrow], Ls[k8 + 5][nrow]);
            o.w = pk_bf16(Ls[k8 + 6][nrow], Ls[k8 + 7][nrow]);
            *(uint4*)&Bs[nrow][k8] = o;
        }
        __syncthreads();
        #pragma unroll
        for (int kt = 0; kt < 2; ++kt) {
            const bf16x8 b8 = *(const bf16x8*)&Bs[w * 16 + l16][kt * 32 + quad * 8];
            #pragma unroll
            for (int mt = 0; mt < 4; ++mt) {
                const bf16x8 a8 = *(const bf16x8*)&As[mt * 16 + l16][kt * 32 + quad * 8];
                acc[mt] = __builtin_amdgcn_mfma_f32_16x16x32_bf16(a8, b8, acc[mt], 0, 0, 0);
            }
        }
    }
    const int n = n0 + w * 16 + l16;
    #pragma unroll
    for (int mt = 0; mt < 4; ++mt)
        #pragma unroll
        for (int r = 0; r < 4; ++r) {
            const int mrow = m0 + mt * 16 + quad * 4 + r;
            OUT[(size_t)mrow * 512 + n] = acc[mt][r];
        }
}

extern "C" void kernel_launch(void* const* d_in, const int* in_sizes, int n_in,
                              void* d_out, int out_size, void* d_ws, size_t ws_size,
                              hipStream_t stream)
{
    const float* x   = (const float*)d_in[0];
    const float* Wp0 = (const float*)d_in[1];
    const float* Wp1 = (const float*)d_in[2];
    const float* Wp2 = (const float*)d_in[3];
    const float* Wv0 = (const float*)d_in[4];
    const float* Wv1 = (const float*)d_in[5];
    const float* Wc  = (const float*)d_in[6];
    float* out = (float*)d_out;

    char* w8 = (char*)d_ws;
    const size_t HB = 512 * 1024;
    unsigned short* p0b = (unsigned short*)(w8 + 0 * HB);
    unsigned short* p1b = (unsigned short*)(w8 + 1 * HB);
    unsigned short* p2b = (unsigned short*)(w8 + 2 * HB);
    unsigned short* Yb  = (unsigned short*)(w8 + 3 * HB);
    float*          rr  = (float*)        (w8 + 4 * HB);

    proj_kernel <<<dim3(8, 8, 3), 256, 0, stream>>>(x, Wp0, Wp1, Wp2, p0b, p1b, p2b, rr);
    attn_kernel <<<dim3(512), 512, 0, stream>>>(p0b, p1b, p2b, rr, Wv0, Wv1, Yb);
    outmm_kernel<<<dim3(8, 8), 256, 0, stream>>>(Yb, Wc, out);
}

// Round 9
// 111.145 us; speedup vs baseline: 1.1281x; 1.0241x over previous
//
#include <hip/hip_runtime.h>
#include <hip/hip_bf16.h>
#include <math.h>

#define B 4
#define T 128
#define C 512
#define NH 8
#define HS 64
#define BH (B*NH)   // 32

typedef __attribute__((ext_vector_type(8))) short bf16x8;
typedef __attribute__((ext_vector_type(4))) float f32x4;

__device__ __forceinline__ unsigned short bfc(float x) {
    return __builtin_bit_cast(unsigned short, __float2bfloat16(x));
}
__device__ __forceinline__ unsigned int pk_bf16(float a, float b) {
    return (unsigned int)bfc(a) | ((unsigned int)bfc(b) << 16);
}
__device__ __forceinline__ float lo_f(unsigned int g) {
    return __builtin_bit_cast(float, g << 16);
}
__device__ __forceinline__ float hi_f(unsigned int g) {
    return __builtin_bit_cast(float, g & 0xffff0000u);
}

// ---------------- K1: p{0,1,2} = X @ Wp{0,1,2}  (fp32 in, bf16 out, on-the-fly cvt+transpose)
// m-tile 32 -> 384 blocks (full CU coverage). z==2 additionally emits rr = rowsums(p2).
__global__ __launch_bounds__(256) void proj_kernel(
    const float* __restrict__ X,
    const float* __restrict__ Wp0, const float* __restrict__ Wp1, const float* __restrict__ Wp2,
    unsigned short* __restrict__ p0b, unsigned short* __restrict__ p1b,
    unsigned short* __restrict__ p2b, float* __restrict__ rr)
{
    __shared__ __align__(16) unsigned short As[32][72];
    __shared__ __align__(16) unsigned short Bs[64][72];
    __shared__ float Ls[64][69];
    __shared__ float sRS[4][32];
    const int z = blockIdx.z;
    const float* W = (z == 0) ? Wp0 : (z == 1) ? Wp1 : Wp2;
    const int m0 = blockIdx.y * 32, n0 = blockIdx.x * 64;
    const int tid = threadIdx.x;
    const int w = tid >> 6, lane = tid & 63, quad = lane >> 4, l16 = lane & 15;
    f32x4 acc[2];
    #pragma unroll
    for (int mt = 0; mt < 2; ++mt) acc[mt] = (f32x4){0.f, 0.f, 0.f, 0.f};

    for (int k0 = 0; k0 < 512; k0 += 64) {
        __syncthreads();
        {
            const int row = tid >> 3, c8 = (tid & 7) * 8;
            const float4 a = *(const float4*)&X[(size_t)(m0 + row) * 512 + k0 + c8];
            const float4 b = *(const float4*)&X[(size_t)(m0 + row) * 512 + k0 + c8 + 4];
            uint4 o;
            o.x = pk_bf16(a.x, a.y);
            o.y = pk_bf16(a.z, a.w);
            o.z = pk_bf16(b.x, b.y);
            o.w = pk_bf16(b.z, b.w);
            *(uint4*)&As[row][c8] = o;
        }
        #pragma unroll
        for (int it = 0; it < 4; ++it) {
            const int q = tid + it * 256;
            const int row = q >> 4, c4 = (q & 15) * 4;
            const float4 v = *(const float4*)&W[(size_t)(k0 + row) * 512 + n0 + c4];
            Ls[row][c4 + 0] = v.x; Ls[row][c4 + 1] = v.y;
            Ls[row][c4 + 2] = v.z; Ls[row][c4 + 3] = v.w;
        }
        __syncthreads();
        #pragma unroll
        for (int it = 0; it < 2; ++it) {
            const int q = tid + it * 256;
            const int nrow = q >> 3, k8 = (q & 7) * 8;
            uint4 o;
            o.x = pk_bf16(Ls[k8 + 0][nrow], Ls[k8 + 1][nrow]);
            o.y = pk_bf16(Ls[k8 + 2][nrow], Ls[k8 + 3][nrow]);
            o.z = pk_bf16(Ls[k8 + 4][nrow], Ls[k8 + 5][nrow]);
            o.w = pk_bf16(Ls[k8 + 6][nrow], Ls[k8 + 7][nrow]);
            *(uint4*)&Bs[nrow][k8] = o;
        }
        __syncthreads();
        #pragma unroll
        for (int kt = 0; kt < 2; ++kt) {
            const bf16x8 b8 = *(const bf16x8*)&Bs[w * 16 + l16][kt * 32 + quad * 8];
            #pragma unroll
            for (int mt = 0; mt < 2; ++mt) {
                const bf16x8 a8 = *(const bf16x8*)&As[mt * 16 + l16][kt * 32 + quad * 8];
                acc[mt] = __builtin_amdgcn_mfma_f32_16x16x32_bf16(a8, b8, acc[mt], 0, 0, 0);
            }
        }
    }

    {
        const int n = n0 + w * 16 + l16;
        const int h = n >> 6, d = n & 63;
        unsigned short* pz = (z == 0) ? p0b : (z == 1) ? p1b : p2b;
        #pragma unroll
        for (int mt = 0; mt < 2; ++mt) {
            #pragma unroll
            for (int r = 0; r < 4; ++r) {
                const int m = m0 + mt * 16 + quad * 4 + r;
                const int bb = m >> 7, t = m & 127;
                pz[((size_t)(bb * NH + h) * T + t) * HS + d] = bfc(acc[mt][r]);
            }
        }
    }
    if (z == 2) {
        #pragma unroll
        for (int mt = 0; mt < 2; ++mt)
            #pragma unroll
            for (int r = 0; r < 4; ++r) {
                float v = acc[mt][r];
                v += __shfl_xor(v, 1, 64); v += __shfl_xor(v, 2, 64);
                v += __shfl_xor(v, 4, 64); v += __shfl_xor(v, 8, 64);
                if (l16 == 0) sRS[w][mt * 16 + quad * 4 + r] = v;
            }
        __syncthreads();
        if (tid < 32) {
            const float s = sRS[0][tid] + sRS[1][tid] + sRS[2][tid] + sRS[3][tid];
            const int m = m0 + tid, bb = m >> 7, tl = m & 127, h = n0 >> 6;
            rr[(bb * NH + h) * T + tl] = s;
        }
    }
}

// ---------------- K2: attention; 512 blocks x 512 threads (8 waves); (bh, ig 0..15) x 8 i's
// double-buffered full-width E, 1 barrier/i; PV split across wave pairs; divide deferred.
__global__ __launch_bounds__(512, 4) void attn_kernel(
    const unsigned short* __restrict__ p0b, const unsigned short* __restrict__ p1b,
    const unsigned short* __restrict__ p2b, const float* __restrict__ rr,
    const float* __restrict__ Wv0, const float* __restrict__ Wv1,
    unsigned short* __restrict__ Yb)
{
    __shared__ __align__(16) union {
        struct {
            unsigned short sWv[64][72];      // Wv^T bf16 [d][k] (one at a time)
            unsigned short sVst[64][136];    // V^T staging [d][t] (V0 then V1)
        } v;                                  // 26.6 KB
        unsigned short sE[2][128 * 128];     // double-buffered full-width E; 64 KB
    } u;
    __shared__ float sS[8][128];
    __shared__ float srr[128];
    __shared__ float sZarr[8][8];            // [qq][wave] Z partials
    __shared__ float sY[8][2][64];           // [qq][mt-half][d] y partials (pre-divide)

    const int bid = blockIdx.x;
    const int bh = bid & (BH - 1);
    const int ig = bid >> 5;                 // 0..15
    const int tid = threadIdx.x;
    const int w = tid >> 6;                  // 0..7
    const int lane = tid & 63;
    const int quad = lane >> 4;
    const int l16 = lane & 15;
    const int wq = w & 3;                    // d-slice group (d = wq*16+l16)
    const int h4 = (w >> 2) * 4;             // mt base: waves 0-3 -> 0, waves 4-7 -> 4

    if (tid < 128) srr[tid] = rr[bh * T + tid];

    // ---- stage Wv0^T ----
    #pragma unroll
    for (int it = 0; it < 2; ++it) {
        const int k = (tid >> 4) + it * 32;
        const int d0 = (tid & 15) * 4;
        const float4 wv = *(const float4*)&Wv0[(size_t)k * 64 + d0];
        u.v.sWv[d0 + 0][k] = bfc(wv.x); u.v.sWv[d0 + 1][k] = bfc(wv.y);
        u.v.sWv[d0 + 2][k] = bfc(wv.z); u.v.sWv[d0 + 3][k] = bfc(wv.w);
    }
    __syncthreads();                                       // bar1: sWv(Wv0) + srr

    // ---- V0 = p1 @ Wv0 -> sVst (wave w covers nt = w) ----
    {
        f32x4 vacc[4];
        #pragma unroll
        for (int mt = 0; mt < 4; ++mt) vacc[mt] = (f32x4){0.f, 0.f, 0.f, 0.f};
        #pragma unroll
        for (int kt = 0; kt < 2; ++kt) {
            const bf16x8 b8 = *(const bf16x8*)&p1b[((size_t)bh * T + w * 16 + l16) * HS + kt * 32 + quad * 8];
            #pragma unroll
            for (int mt = 0; mt < 4; ++mt) {
                const bf16x8 a8 = *(const bf16x8*)&u.v.sWv[mt * 16 + l16][kt * 32 + quad * 8];
                vacc[mt] = __builtin_amdgcn_mfma_f32_16x16x32_bf16(a8, b8, vacc[mt], 0, 0, 0);
            }
        }
        #pragma unroll
        for (int mt = 0; mt < 4; ++mt)
            #pragma unroll
            for (int r = 0; r < 4; ++r)
                u.v.sVst[mt * 16 + quad * 4 + r][w * 16 + l16] = bfc(vacc[mt][r]);
    }
    __syncthreads();                                       // bar2: sVst(V0)

    // ---- v0 regs (this wave's mt-half of its d-slice) + stage Wv1^T ----
    uint2 v0r[4];
    #pragma unroll
    for (int m = 0; m < 4; ++m)
        v0r[m] = *(const uint2*)&u.v.sVst[(wq << 4) + l16][((h4 + m) << 4) + (quad << 2)];
    #pragma unroll
    for (int it = 0; it < 2; ++it) {
        const int k = (tid >> 4) + it * 32;
        const int d0 = (tid & 15) * 4;
        const float4 wv = *(const float4*)&Wv1[(size_t)k * 64 + d0];
        u.v.sWv[d0 + 0][k] = bfc(wv.x); u.v.sWv[d0 + 1][k] = bfc(wv.y);
        u.v.sWv[d0 + 2][k] = bfc(wv.z); u.v.sWv[d0 + 3][k] = bfc(wv.w);
    }
    __syncthreads();                                       // bar3: v0r read + sWv(Wv1)

    // ---- V1 = p2 @ Wv1 -> sVst ----
    {
        f32x4 vacc[4];
        #pragma unroll
        for (int mt = 0; mt < 4; ++mt) vacc[mt] = (f32x4){0.f, 0.f, 0.f, 0.f};
        #pragma unroll
        for (int kt = 0; kt < 2; ++kt) {
            const bf16x8 b8 = *(const bf16x8*)&p2b[((size_t)bh * T + w * 16 + l16) * HS + kt * 32 + quad * 8];
            #pragma unroll
            for (int mt = 0; mt < 4; ++mt) {
                const bf16x8 a8 = *(const bf16x8*)&u.v.sWv[mt * 16 + l16][kt * 32 + quad * 8];
                vacc[mt] = __builtin_amdgcn_mfma_f32_16x16x32_bf16(a8, b8, vacc[mt], 0, 0, 0);
            }
        }
        #pragma unroll
        for (int mt = 0; mt < 4; ++mt)
            #pragma unroll
            for (int r = 0; r < 4; ++r)
                u.v.sVst[mt * 16 + quad * 4 + r][w * 16 + l16] = bfc(vacc[mt][r]);
    }
    __syncthreads();                                       // bar4: sVst(V1)

    // ---- v1 regs + all 8 S rows (wave w covers j = w*16+l16) ----
    uint4 v1r[4];
    #pragma unroll
    for (int kt = 0; kt < 4; ++kt)
        v1r[kt] = *(const uint4*)&u.v.sVst[(wq << 4) + l16][(quad << 3) + (kt << 5)];
    {
        const int qr = l16 & 7;
        const int irow = (qr & 1) ? (16 * qr + 15 - ig) : (16 * qr + ig);
        const unsigned short* ap = p0b + ((size_t)bh * T + irow) * HS + (quad << 3);
        const unsigned short* bp = p1b + (size_t)bh * T * HS + (quad << 3);
        f32x4 s0 = (f32x4){0.f, 0.f, 0.f, 0.f};
        #pragma unroll
        for (int kt = 0; kt < 2; ++kt) {
            const bf16x8 a8 = *(const bf16x8*)(ap + (kt << 5));
            const bf16x8 b0 = *(const bf16x8*)(bp + (size_t)((w << 4) + l16) * HS + (kt << 5));
            s0 = __builtin_amdgcn_mfma_f32_16x16x32_bf16(a8, b0, s0, 0, 0, 0);
        }
        if (quad < 2) {
            #pragma unroll
            for (int r = 0; r < 4; ++r)
                sS[quad * 4 + r][(w << 4) + l16] = s0[r] * 0.125f;
        }
    }
    __syncthreads();                                       // bar5: sS ready; v1r read; sE usable

    const float L2E = 1.4426950408889634f;

    // ---- hoisted: global mhat (upper bound via shift-invariance) + rk + bexp ----
    float mhat;
    {
        float aS = 0.f;
        #pragma unroll
        for (int q = 0; q < 8; ++q) {
            aS = fmaxf(aS, fabsf(sS[q][lane]));
            aS = fmaxf(aS, fabsf(sS[q][64 + lane]));
        }
        float aR = fmaxf(fabsf(srr[lane]), fabsf(srr[64 + lane]));
        #pragma unroll
        for (int off = 32; off; off >>= 1) {
            aS = fmaxf(aS, __shfl_xor(aS, off, 64));
            aR = fmaxf(aR, __shfl_xor(aR, off, 64));
        }
        mhat = aS * aR;
    }
    const float bexp = -mhat * L2E;
    const int cc = tid & 15;           // 16B chunk (8 bf16 cols) of the 128-col row
    const int rowin = tid >> 4;        // row within 32-row pass (0..31)
    const int k0l = cc << 3;
    float rk[8];
    *(float4*)&rk[0] = *(const float4*)&srr[k0l];
    *(float4*)&rk[4] = *(const float4*)&srr[k0l + 4];

    for (int qq = 7; qq >= 0; --qq) {                      // biggest i first
        const int i = (qq & 1) ? (16 * qq + 15 - ig) : (16 * qq + ig);
        const float* sSq = sS[qq];
        const int mtmax = i >> 4;
        const int buf = qq & 1;
        float zacc = 0.f;

        // ---- full-width E build into buf (32 rows/pass) ----
        const int npass = (mtmax + 2) >> 1;
        for (int p = 0; p < npass; ++p) {
            const int jj = (p << 5) + rowin;
            uint4 o = {0u, 0u, 0u, 0u};
            if (jj <= i && k0l <= jj) {
                const float aL = sSq[jj] * L2E;
                const int dlim = jj - k0l;
                float e[8];
                #pragma unroll
                for (int q = 0; q < 8; ++q) {
                    const float ex = __builtin_amdgcn_exp2f(fmaf(aL, rk[q], bexp));
                    e[q] = (q <= dlim) ? ex : 0.f;
                    zacc += e[q];
                }
                o.x = pk_bf16(e[0], e[1]);
                o.y = pk_bf16(e[2], e[3]);
                o.z = pk_bf16(e[4], e[5]);
                o.w = pk_bf16(e[6], e[7]);
            }
            *(uint4*)&u.sE[buf][(jj << 7) + ((cc ^ (jj & 7)) << 3)] = o;
        }
        #pragma unroll
        for (int off = 32; off; off >>= 1) zacc += __shfl_xor(zacc, off, 64);
        if (lane == 0) sZarr[qq][w] = zacc;
        __syncthreads();                                   // E[buf] ready; prev MFMA drained

        // ---- PV MFMA from buf: wave handles its mt-half ----
        f32x4 acc[4];
        #pragma unroll
        for (int m = 0; m < 4; ++m) acc[m] = (f32x4){0.f, 0.f, 0.f, 0.f};
        #pragma unroll
        for (int mtl = 0; mtl < 4; ++mtl) {
            const int mt = h4 + mtl;
            if (mt <= mtmax) {
                #pragma unroll
                for (int kt = 0; kt < 4; ++kt) {
                    if (kt <= (mt >> 1)) {
                        const int ch = ((kt << 2) + quad) ^ (l16 & 7);
                        const bf16x8 a8 = *(const bf16x8*)&u.sE[buf][(((mt << 4) + l16) << 7) + (ch << 3)];
                        acc[mtl] = __builtin_amdgcn_mfma_f32_16x16x32_bf16(
                            a8, __builtin_bit_cast(bf16x8, v1r[kt]), acc[mtl], 0, 0, 0);
                    }
                }
            }
        }

        // ---- partial epilogue (no divide): sum over this wave's mt-half ----
        float part = 0.f;
        #pragma unroll
        for (int mtl = 0; mtl < 4; ++mtl) {
            const int mt = h4 + mtl;
            if (mt < mtmax) {
                const uint2 uu = v0r[mtl];
                part = fmaf(lo_f(uu.x), acc[mtl][0], part);
                part = fmaf(hi_f(uu.x), acc[mtl][1], part);
                part = fmaf(lo_f(uu.y), acc[mtl][2], part);
                part = fmaf(hi_f(uu.y), acc[mtl][3], part);
            } else if (mt == mtmax) {
                const uint2 uu = v0r[mtl];
                const int jb = (mt << 4) + (quad << 2);
                if (jb + 0 <= i) part = fmaf(lo_f(uu.x), acc[mtl][0], part);
                if (jb + 1 <= i) part = fmaf(hi_f(uu.x), acc[mtl][1], part);
                if (jb + 2 <= i) part = fmaf(lo_f(uu.y), acc[mtl][2], part);
                if (jb + 3 <= i) part = fmaf(hi_f(uu.y), acc[mtl][3], part);
            }
        }
        part += __shfl_xor(part, 16, 64);
        part += __shfl_xor(part, 32, 64);
        if (lane < 16) sY[qq][w >> 2][(wq << 4) + l16] = part;
        // no trailing barrier: next build targets the other buffer.
    }

    // ---- final combine + store: wave w -> qq = w, d = lane ----
    __syncthreads();
    {
        const int qq = w;
        const int d = lane;
        const int i = (qq & 1) ? (16 * qq + 15 - ig) : (16 * qq + ig);
        float Z = 0.f;
        #pragma unroll
        for (int ww = 0; ww < 8; ++ww) Z += sZarr[qq][ww];
        const float y = sY[qq][0][d] + sY[qq][1][d];
        const int bb = bh >> 3, hh = bh & 7;
        Yb[((size_t)(bb * T + i) * C) + hh * HS + d] = bfc(y / Z);
    }
}

// ---------------- K3: OUT = Yb @ Wc (bf16 A, fp32 W transposed on the fly, fp32 out)
// m-tile 32 -> 128 blocks (2x CU coverage).
__global__ __launch_bounds__(256) void outmm_kernel(
    const unsigned short* __restrict__ Ab, const float* __restrict__ Wc,
    float* __restrict__ OUT)
{
    __shared__ __align__(16) unsigned short As[32][72];
    __shared__ __align__(16) unsigned short Bs[64][72];
    __shared__ float Ls[64][69];
    const int m0 = blockIdx.y * 32, n0 = blockIdx.x * 64;
    const int tid = threadIdx.x;
    const int w = tid >> 6, lane = tid & 63, quad = lane >> 4, l16 = lane & 15;
    f32x4 acc[2];
    #pragma unroll
    for (int mt = 0; mt < 2; ++mt) acc[mt] = (f32x4){0.f, 0.f, 0.f, 0.f};
    for (int k0 = 0; k0 < 512; k0 += 64) {
        __syncthreads();
        {
            const int row = tid >> 3, c8 = (tid & 7) * 8;
            *(uint4*)&As[row][c8] = *(const uint4*)&Ab[(size_t)(m0 + row) * 512 + k0 + c8];
        }
        #pragma unroll
        for (int it = 0; it < 4; ++it) {
            const int q = tid + it * 256;
            const int row = q >> 4, c4 = (q & 15) * 4;
            const float4 v = *(const float4*)&Wc[(size_t)(k0 + row) * 512 + n0 + c4];
            Ls[row][c4 + 0] = v.x; Ls[row][c4 + 1] = v.y;
            Ls[row][c4 + 2] = v.z; Ls[row][c4 + 3] = v.w;
        }
        __syncthreads();
        #pragma unroll
        for (int it = 0; it < 2; ++it) {
            const int q = tid + it * 256;
            const int nrow = q >> 3, k8 = (q & 7) * 8;
            uint4 o;
            o.x = pk_bf16(Ls[k8 + 0][nrow], Ls[k8 + 1][nrow]);
            o.y = pk_bf16(Ls[k8 + 2][nrow], Ls[k8 + 3][nrow]);
            o.z = pk_bf16(Ls[k8 + 4][nrow], Ls[k8 + 5][nrow]);
            o.w = pk_bf16(Ls[k8 + 6][nrow], Ls[k8 + 7][nrow]);
            *(uint4*)&Bs[nrow][k8] = o;
        }
        __syncthreads();
        #pragma unroll
        for (int kt = 0; kt < 2; ++kt) {
            const bf16x8 b8 = *(const bf16x8*)&Bs[w * 16 + l16][kt * 32 + quad * 8];
            #pragma unroll
            for (int mt = 0; mt < 2; ++mt) {
                const bf16x8 a8 = *(const bf16x8*)&As[mt * 16 + l16][kt * 32 + quad * 8];
                acc[mt] = __builtin_amdgcn_mfma_f32_16x16x32_bf16(a8, b8, acc[mt], 0, 0, 0);
            }
        }
    }
    const int n = n0 + w * 16 + l16;
    #pragma unroll
    for (int mt = 0; mt < 2; ++mt)
        #pragma unroll
        for (int r = 0; r < 4; ++r) {
            const int mrow = m0 + mt * 16 + quad * 4 + r;
            OUT[(size_t)mrow * 512 + n] = acc[mt][r];
        }
}

extern "C" void kernel_launch(void* const* d_in, const int* in_sizes, int n_in,
                              void* d_out, int out_size, void* d_ws, size_t ws_size,
                              hipStream_t stream)
{
    const float* x   = (const float*)d_in[0];
    const float* Wp0 = (const float*)d_in[1];
    const float* Wp1 = (const float*)d_in[2];
    const float* Wp2 = (const float*)d_in[3];
    const float* Wv0 = (const float*)d_in[4];
    const float* Wv1 = (const float*)d_in[5];
    const float* Wc  = (const float*)d_in[6];
    float* out = (float*)d_out;

    char* w8 = (char*)d_ws;
    const size_t HB = 512 * 1024;
    unsigned short* p0b = (unsigned short*)(w8 + 0 * HB);
    unsigned short* p1b = (unsigned short*)(w8 + 1 * HB);
    unsigned short* p2b = (unsigned short*)(w8 + 2 * HB);
    unsigned short* Yb  = (unsigned short*)(w8 + 3 * HB);
    float*          rr  = (float*)        (w8 + 4 * HB);

    proj_kernel <<<dim3(8, 16, 3), 256, 0, stream>>>(x, Wp0, Wp1, Wp2, p0b, p1b, p2b, rr);
    attn_kernel <<<dim3(512), 512, 0, stream>>>(p0b, p1b, p2b, rr, Wv0, Wv1, Yb);
    outmm_kernel<<<dim3(8, 16), 256, 0, stream>>>(Yb, Wc, out);
}

// Round 10
// 103.973 us; speedup vs baseline: 1.2059x; 1.0690x over previous
//
#include <hip/hip_runtime.h>
#include <hip/hip_bf16.h>
#include <math.h>

#define B 4
#define T 128
#define C 512
#define NH 8
#define HS 64
#define BH (B*NH)   // 32

typedef __attribute__((ext_vector_type(8))) short bf16x8;
typedef __attribute__((ext_vector_type(4))) float f32x4;

__device__ __forceinline__ unsigned short bfc(float x) {
    return __builtin_bit_cast(unsigned short, __float2bfloat16(x));
}
__device__ __forceinline__ unsigned int pk_bf16(float a, float b) {
    return (unsigned int)bfc(a) | ((unsigned int)bfc(b) << 16);
}
__device__ __forceinline__ float lo_f(unsigned int g) {
    return __builtin_bit_cast(float, g << 16);
}
__device__ __forceinline__ float hi_f(unsigned int g) {
    return __builtin_bit_cast(float, g & 0xffff0000u);
}

// ---------------- K1: p{0,1,2} = X @ Wp{0,1,2}  (fp32 in, bf16 out, on-the-fly cvt+transpose)
// m-tile 32 -> 384 blocks. z==2 additionally emits rr = rowsums(p2).
__global__ __launch_bounds__(256) void proj_kernel(
    const float* __restrict__ X,
    const float* __restrict__ Wp0, const float* __restrict__ Wp1, const float* __restrict__ Wp2,
    unsigned short* __restrict__ p0b, unsigned short* __restrict__ p1b,
    unsigned short* __restrict__ p2b, float* __restrict__ rr)
{
    __shared__ __align__(16) unsigned short As[32][72];
    __shared__ __align__(16) unsigned short Bs[64][72];
    __shared__ float Ls[64][69];
    __shared__ float sRS[4][32];
    const int z = blockIdx.z;
    const float* W = (z == 0) ? Wp0 : (z == 1) ? Wp1 : Wp2;
    const int m0 = blockIdx.y * 32, n0 = blockIdx.x * 64;
    const int tid = threadIdx.x;
    const int w = tid >> 6, lane = tid & 63, quad = lane >> 4, l16 = lane & 15;
    f32x4 acc[2];
    #pragma unroll
    for (int mt = 0; mt < 2; ++mt) acc[mt] = (f32x4){0.f, 0.f, 0.f, 0.f};

    for (int k0 = 0; k0 < 512; k0 += 64) {
        __syncthreads();
        {
            const int row = tid >> 3, c8 = (tid & 7) * 8;
            const float4 a = *(const float4*)&X[(size_t)(m0 + row) * 512 + k0 + c8];
            const float4 b = *(const float4*)&X[(size_t)(m0 + row) * 512 + k0 + c8 + 4];
            uint4 o;
            o.x = pk_bf16(a.x, a.y);
            o.y = pk_bf16(a.z, a.w);
            o.z = pk_bf16(b.x, b.y);
            o.w = pk_bf16(b.z, b.w);
            *(uint4*)&As[row][c8] = o;
        }
        #pragma unroll
        for (int it = 0; it < 4; ++it) {
            const int q = tid + it * 256;
            const int row = q >> 4, c4 = (q & 15) * 4;
            const float4 v = *(const float4*)&W[(size_t)(k0 + row) * 512 + n0 + c4];
            Ls[row][c4 + 0] = v.x; Ls[row][c4 + 1] = v.y;
            Ls[row][c4 + 2] = v.z; Ls[row][c4 + 3] = v.w;
        }
        __syncthreads();
        #pragma unroll
        for (int it = 0; it < 2; ++it) {
            const int q = tid + it * 256;
            const int nrow = q >> 3, k8 = (q & 7) * 8;
            uint4 o;
            o.x = pk_bf16(Ls[k8 + 0][nrow], Ls[k8 + 1][nrow]);
            o.y = pk_bf16(Ls[k8 + 2][nrow], Ls[k8 + 3][nrow]);
            o.z = pk_bf16(Ls[k8 + 4][nrow], Ls[k8 + 5][nrow]);
            o.w = pk_bf16(Ls[k8 + 6][nrow], Ls[k8 + 7][nrow]);
            *(uint4*)&Bs[nrow][k8] = o;
        }
        __syncthreads();
        #pragma unroll
        for (int kt = 0; kt < 2; ++kt) {
            const bf16x8 b8 = *(const bf16x8*)&Bs[w * 16 + l16][kt * 32 + quad * 8];
            #pragma unroll
            for (int mt = 0; mt < 2; ++mt) {
                const bf16x8 a8 = *(const bf16x8*)&As[mt * 16 + l16][kt * 32 + quad * 8];
                acc[mt] = __builtin_amdgcn_mfma_f32_16x16x32_bf16(a8, b8, acc[mt], 0, 0, 0);
            }
        }
    }

    {
        const int n = n0 + w * 16 + l16;
        const int h = n >> 6, d = n & 63;
        unsigned short* pz = (z == 0) ? p0b : (z == 1) ? p1b : p2b;
        #pragma unroll
        for (int mt = 0; mt < 2; ++mt) {
            #pragma unroll
            for (int r = 0; r < 4; ++r) {
                const int m = m0 + mt * 16 + quad * 4 + r;
                const int bb = m >> 7, t = m & 127;
                pz[((size_t)(bb * NH + h) * T + t) * HS + d] = bfc(acc[mt][r]);
            }
        }
    }
    if (z == 2) {
        #pragma unroll
        for (int mt = 0; mt < 2; ++mt)
            #pragma unroll
            for (int r = 0; r < 4; ++r) {
                float v = acc[mt][r];
                v += __shfl_xor(v, 1, 64); v += __shfl_xor(v, 2, 64);
                v += __shfl_xor(v, 4, 64); v += __shfl_xor(v, 8, 64);
                if (l16 == 0) sRS[w][mt * 16 + quad * 4 + r] = v;
            }
        __syncthreads();
        if (tid < 32) {
            const float s = sRS[0][tid] + sRS[1][tid] + sRS[2][tid] + sRS[3][tid];
            const int m = m0 + tid, bb = m >> 7, tl = m & 127, h = n0 >> 6;
            rr[(bb * NH + h) * T + tl] = s;
        }
    }
}

// ---------------- K2: attention; 512 blocks x 512 threads (8 waves); (bh, ig) x 8 i's
// A-fragments built in REGISTERS (no E in LDS); wave w owns row-tile mt=w; ZERO loop barriers.
__global__ __launch_bounds__(512, 4) void attn_kernel(
    const unsigned short* __restrict__ p0b, const unsigned short* __restrict__ p1b,
    const unsigned short* __restrict__ p2b, const float* __restrict__ rr,
    const float* __restrict__ Wv0, const float* __restrict__ Wv1,
    unsigned short* __restrict__ Yb)
{
    __shared__ __align__(16) unsigned short sV0T[64][136];   // V0^T [d][t], persistent
    __shared__ __align__(16) unsigned short sV1T[64][136];   // V1^T [d][t], persistent
    __shared__ __align__(16) union {
        unsigned short sWv[64][72];                          // Wv^T bf16 (transient, prologue)
        float sY[8][8][64];                                  // [qq][wave][d] y partials
    } u2;
    __shared__ float sS[8][128];
    __shared__ float srr[128];
    __shared__ float sZarr[8][8];                            // [qq][wave] Z partials

    const int bid = blockIdx.x;
    const int bh = bid & (BH - 1);
    const int ig = bid >> 5;                 // 0..15
    const int tid = threadIdx.x;
    const int w = tid >> 6;                  // 0..7 : wave owns row-tile mt = w
    const int lane = tid & 63;
    const int quad = lane >> 4;
    const int l16 = lane & 15;

    if (tid < 128) srr[tid] = rr[bh * T + tid];

    // ---- stage Wv0^T ----
    #pragma unroll
    for (int it = 0; it < 2; ++it) {
        const int k = (tid >> 4) + it * 32;
        const int d0 = (tid & 15) * 4;
        const float4 wv = *(const float4*)&Wv0[(size_t)k * 64 + d0];
        u2.sWv[d0 + 0][k] = bfc(wv.x); u2.sWv[d0 + 1][k] = bfc(wv.y);
        u2.sWv[d0 + 2][k] = bfc(wv.z); u2.sWv[d0 + 3][k] = bfc(wv.w);
    }
    __syncthreads();                                       // bar1: sWv(Wv0) + srr

    // ---- V0 = p1 @ Wv0 -> sV0T (wave w covers nt = w) ----
    {
        f32x4 vacc[4];
        #pragma unroll
        for (int mt = 0; mt < 4; ++mt) vacc[mt] = (f32x4){0.f, 0.f, 0.f, 0.f};
        #pragma unroll
        for (int kt = 0; kt < 2; ++kt) {
            const bf16x8 b8 = *(const bf16x8*)&p1b[((size_t)bh * T + w * 16 + l16) * HS + kt * 32 + quad * 8];
            #pragma unroll
            for (int mt = 0; mt < 4; ++mt) {
                const bf16x8 a8 = *(const bf16x8*)&u2.sWv[mt * 16 + l16][kt * 32 + quad * 8];
                vacc[mt] = __builtin_amdgcn_mfma_f32_16x16x32_bf16(a8, b8, vacc[mt], 0, 0, 0);
            }
        }
        #pragma unroll
        for (int mt = 0; mt < 4; ++mt)
            #pragma unroll
            for (int r = 0; r < 4; ++r)
                sV0T[mt * 16 + quad * 4 + r][w * 16 + l16] = bfc(vacc[mt][r]);
    }
    __syncthreads();                                       // bar2: sWv reads drained

    // ---- stage Wv1^T ----
    #pragma unroll
    for (int it = 0; it < 2; ++it) {
        const int k = (tid >> 4) + it * 32;
        const int d0 = (tid & 15) * 4;
        const float4 wv = *(const float4*)&Wv1[(size_t)k * 64 + d0];
        u2.sWv[d0 + 0][k] = bfc(wv.x); u2.sWv[d0 + 1][k] = bfc(wv.y);
        u2.sWv[d0 + 2][k] = bfc(wv.z); u2.sWv[d0 + 3][k] = bfc(wv.w);
    }
    __syncthreads();                                       // bar3: sWv(Wv1) ready

    // ---- V1 = p2 @ Wv1 -> sV1T ----
    {
        f32x4 vacc[4];
        #pragma unroll
        for (int mt = 0; mt < 4; ++mt) vacc[mt] = (f32x4){0.f, 0.f, 0.f, 0.f};
        #pragma unroll
        for (int kt = 0; kt < 2; ++kt) {
            const bf16x8 b8 = *(const bf16x8*)&p2b[((size_t)bh * T + w * 16 + l16) * HS + kt * 32 + quad * 8];
            #pragma unroll
            for (int mt = 0; mt < 4; ++mt) {
                const bf16x8 a8 = *(const bf16x8*)&u2.sWv[mt * 16 + l16][kt * 32 + quad * 8];
                vacc[mt] = __builtin_amdgcn_mfma_f32_16x16x32_bf16(a8, b8, vacc[mt], 0, 0, 0);
            }
        }
        #pragma unroll
        for (int mt = 0; mt < 4; ++mt)
            #pragma unroll
            for (int r = 0; r < 4; ++r)
                sV1T[mt * 16 + quad * 4 + r][w * 16 + l16] = bfc(vacc[mt][r]);
    }
    __syncthreads();                                       // bar4: sV1T done; sWv dead -> sY usable

    // ---- all 8 S rows (wave w covers j = w*16+l16) + zero sY/sZarr ----
    {
        const int qr = l16 & 7;
        const int irow = (qr & 1) ? (16 * qr + 15 - ig) : (16 * qr + ig);
        const unsigned short* ap = p0b + ((size_t)bh * T + irow) * HS + (quad << 3);
        const unsigned short* bp = p1b + (size_t)bh * T * HS + (quad << 3);
        f32x4 s0 = (f32x4){0.f, 0.f, 0.f, 0.f};
        #pragma unroll
        for (int kt = 0; kt < 2; ++kt) {
            const bf16x8 a8 = *(const bf16x8*)(ap + (kt << 5));
            const bf16x8 b0 = *(const bf16x8*)(bp + (size_t)((w << 4) + l16) * HS + (kt << 5));
            s0 = __builtin_amdgcn_mfma_f32_16x16x32_bf16(a8, b0, s0, 0, 0, 0);
        }
        if (quad < 2) {
            #pragma unroll
            for (int r = 0; r < 4; ++r)
                sS[quad * 4 + r][(w << 4) + l16] = s0[r] * 0.125f;
        }
    }
    #pragma unroll
    for (int it = 0; it < 8; ++it) ((float*)u2.sY)[tid + it * 512] = 0.f;
    if (tid < 64) ((float*)sZarr)[tid] = 0.f;
    __syncthreads();                                       // bar5: sS, sY=0, sZarr=0, sV0T/sV1T ready

    const float L2E = 1.4426950408889634f;

    // ---- hoisted global mhat (upper bound via shift-invariance) ----
    float mhat;
    {
        float aS = 0.f;
        #pragma unroll
        for (int q = 0; q < 8; ++q) {
            aS = fmaxf(aS, fabsf(sS[q][lane]));
            aS = fmaxf(aS, fabsf(sS[q][64 + lane]));
        }
        float aR = fmaxf(fabsf(srr[lane]), fabsf(srr[64 + lane]));
        #pragma unroll
        for (int off = 32; off; off >>= 1) {
            aS = fmaxf(aS, __shfl_xor(aS, off, 64));
            aR = fmaxf(aR, __shfl_xor(aR, off, 64));
        }
        mhat = aS * aR;
    }
    const float bexp = -mhat * L2E;
    const int jrow = (w << 4) + l16;         // this lane's A-row (j index)
    const int ktmax = w >> 1;                // k-tiles needed for this row-tile

    // ---- BARRIER-FREE loop: wave w participates in qq >= w (mtmax == qq) ----
    for (int qq = 7; qq >= w; --qq) {
        const int i = (qq & 1) ? (16 * qq + 15 - ig) : (16 * qq + ig);
        const float aL = sS[qq][jrow] * L2E;
        const bool rowok = (jrow <= i);
        f32x4 acc[4];
        #pragma unroll
        for (int dt = 0; dt < 4; ++dt) acc[dt] = (f32x4){0.f, 0.f, 0.f, 0.f};
        float zacc = 0.f;

        for (int kt = 0; kt <= ktmax; ++kt) {
            const int kbase = (kt << 5) + (quad << 3);
            float rk[8];
            *(float4*)&rk[0] = *(const float4*)&srr[kbase];
            *(float4*)&rk[4] = *(const float4*)&srr[kbase + 4];
            const int dlim = rowok ? (jrow - kbase) : -1;
            float e[8];
            #pragma unroll
            for (int q = 0; q < 8; ++q) {
                const float ex = __builtin_amdgcn_exp2f(fmaf(aL, rk[q], bexp));
                e[q] = (q <= dlim) ? ex : 0.f;
                zacc += e[q];
            }
            uint4 o;
            o.x = pk_bf16(e[0], e[1]);
            o.y = pk_bf16(e[2], e[3]);
            o.z = pk_bf16(e[4], e[5]);
            o.w = pk_bf16(e[6], e[7]);
            const bf16x8 a8 = __builtin_bit_cast(bf16x8, o);
            #pragma unroll
            for (int dt = 0; dt < 4; ++dt) {
                const bf16x8 b8 = *(const bf16x8*)&sV1T[(dt << 4) + l16][(quad << 3) + (kt << 5)];
                acc[dt] = __builtin_amdgcn_mfma_f32_16x16x32_bf16(a8, b8, acc[dt], 0, 0, 0);
            }
        }

        // ---- epilogue: partial y over this wave's row-tile, all 4 d-tiles ----
        float part[4];
        #pragma unroll
        for (int dt = 0; dt < 4; ++dt) {
            const uint2 uu = *(const uint2*)&sV0T[(dt << 4) + l16][(w << 4) + (quad << 2)];
            float p = 0.f;
            if (w < qq) {                                   // all 16 rows of this tile <= i
                p = fmaf(lo_f(uu.x), acc[dt][0], p);
                p = fmaf(hi_f(uu.x), acc[dt][1], p);
                p = fmaf(lo_f(uu.y), acc[dt][2], p);
                p = fmaf(hi_f(uu.y), acc[dt][3], p);
            } else {                                        // w == qq: per-row mask
                const int jb = (w << 4) + (quad << 2);
                if (jb + 0 <= i) p = fmaf(lo_f(uu.x), acc[dt][0], p);
                if (jb + 1 <= i) p = fmaf(hi_f(uu.x), acc[dt][1], p);
                if (jb + 2 <= i) p = fmaf(lo_f(uu.y), acc[dt][2], p);
                if (jb + 3 <= i) p = fmaf(hi_f(uu.y), acc[dt][3], p);
            }
            p += __shfl_xor(p, 16, 64);
            p += __shfl_xor(p, 32, 64);
            part[dt] = p;
        }
        // lane = quad*16+l16 == d; pick this lane's d-tile value
        const float sel = (quad == 0) ? part[0] : (quad == 1) ? part[1] : (quad == 2) ? part[2] : part[3];
        u2.sY[qq][w][lane] = sel;

        #pragma unroll
        for (int off = 32; off; off >>= 1) zacc += __shfl_xor(zacc, off, 64);
        if (lane == 0) sZarr[qq][w] = zacc;
    }
    __syncthreads();                                       // bar6: all partials published

    // ---- final combine + store: wave w -> qq = w, d = lane ----
    {
        const int qq = w;
        const int i = (qq & 1) ? (16 * qq + 15 - ig) : (16 * qq + ig);
        float Z = 0.f;
        #pragma unroll
        for (int ww = 0; ww < 8; ++ww) Z += sZarr[qq][ww];
        float y = 0.f;
        #pragma unroll
        for (int ww = 0; ww < 8; ++ww) y += u2.sY[qq][ww][lane];
        const int bb = bh >> 3, hh = bh & 7;
        Yb[((size_t)(bb * T + i) * C) + hh * HS + lane] = bfc(y / Z);
    }
}

// ---------------- K3: OUT = Yb @ Wc (bf16 A, fp32 W transposed on the fly, fp32 out)
// m-tile 32 -> 128 blocks.
__global__ __launch_bounds__(256) void outmm_kernel(
    const unsigned short* __restrict__ Ab, const float* __restrict__ Wc,
    float* __restrict__ OUT)
{
    __shared__ __align__(16) unsigned short As[32][72];
    __shared__ __align__(16) unsigned short Bs[64][72];
    __shared__ float Ls[64][69];
    const int m0 = blockIdx.y * 32, n0 = blockIdx.x * 64;
    const int tid = threadIdx.x;
    const int w = tid >> 6, lane = tid & 63, quad = lane >> 4, l16 = lane & 15;
    f32x4 acc[2];
    #pragma unroll
    for (int mt = 0; mt < 2; ++mt) acc[mt] = (f32x4){0.f, 0.f, 0.f, 0.f};
    for (int k0 = 0; k0 < 512; k0 += 64) {
        __syncthreads();
        {
            const int row = tid >> 3, c8 = (tid & 7) * 8;
            *(uint4*)&As[row][c8] = *(const uint4*)&Ab[(size_t)(m0 + row) * 512 + k0 + c8];
        }
        #pragma unroll
        for (int it = 0; it < 4; ++it) {
            const int q = tid + it * 256;
            const int row = q >> 4, c4 = (q & 15) * 4;
            const float4 v = *(const float4*)&Wc[(size_t)(k0 + row) * 512 + n0 + c4];
            Ls[row][c4 + 0] = v.x; Ls[row][c4 + 1] = v.y;
            Ls[row][c4 + 2] = v.z; Ls[row][c4 + 3] = v.w;
        }
        __syncthreads();
        #pragma unroll
        for (int it = 0; it < 2; ++it) {
            const int q = tid + it * 256;
            const int nrow = q >> 3, k8 = (q & 7) * 8;
            uint4 o;
            o.x = pk_bf16(Ls[k8 + 0][nrow], Ls[k8 + 1][nrow]);
            o.y = pk_bf16(Ls[k8 + 2][nrow], Ls[k8 + 3][nrow]);
            o.z = pk_bf16(Ls[k8 + 4][nrow], Ls[k8 + 5][nrow]);
            o.w = pk_bf16(Ls[k8 + 6][nrow], Ls[k8 + 7][nrow]);
            *(uint4*)&Bs[nrow][k8] = o;
        }
        __syncthreads();
        #pragma unroll
        for (int kt = 0; kt < 2; ++kt) {
            const bf16x8 b8 = *(const bf16x8*)&Bs[w * 16 + l16][kt * 32 + quad * 8];
            #pragma unroll
            for (int mt = 0; mt < 2; ++mt) {
                const bf16x8 a8 = *(const bf16x8*)&As[mt * 16 + l16][kt * 32 + quad * 8];
                acc[mt] = __builtin_amdgcn_mfma_f32_16x16x32_bf16(a8, b8, acc[mt], 0, 0, 0);
            }
        }
    }
    const int n = n0 + w * 16 + l16;
    #pragma unroll
    for (int mt = 0; mt < 2; ++mt)
        #pragma unroll
        for (int r = 0; r < 4; ++r) {
            const int mrow = m0 + mt * 16 + quad * 4 + r;
            OUT[(size_t)mrow * 512 + n] = acc[mt][r];
        }
}

extern "C" void kernel_launch(void* const* d_in, const int* in_sizes, int n_in,
                              void* d_out, int out_size, void* d_ws, size_t ws_size,
                              hipStream_t stream)
{
    const float* x   = (const float*)d_in[0];
    const float* Wp0 = (const float*)d_in[1];
    const float* Wp1 = (const float*)d_in[2];
    const float* Wp2 = (const float*)d_in[3];
    const float* Wv0 = (const float*)d_in[4];
    const float* Wv1 = (const float*)d_in[5];
    const float* Wc  = (const float*)d_in[6];
    float* out = (float*)d_out;

    char* w8 = (char*)d_ws;
    const size_t HB = 512 * 1024;
    unsigned short* p0b = (unsigned short*)(w8 + 0 * HB);
    unsigned short* p1b = (unsigned short*)(w8 + 1 * HB);
    unsigned short* p2b = (unsigned short*)(w8 + 2 * HB);
    unsigned short* Yb  = (unsigned short*)(w8 + 3 * HB);
    float*          rr  = (float*)        (w8 + 4 * HB);

    proj_kernel <<<dim3(8, 16, 3), 256, 0, stream>>>(x, Wp0, Wp1, Wp2, p0b, p1b, p2b, rr);
    attn_kernel <<<dim3(512), 512, 0, stream>>>(p0b, p1b, p2b, rr, Wv0, Wv1, Yb);
    outmm_kernel<<<dim3(8, 16), 256, 0, stream>>>(Yb, Wc, out);
}

// Round 12
// 99.601 us; speedup vs baseline: 1.2588x; 1.0439x over previous
//
#include <hip/hip_runtime.h>
#include <hip/hip_bf16.h>
#include <math.h>

#define B 4
#define T 128
#define C 512
#define NH 8
#define HS 64
#define BH (B*NH)   // 32

typedef __attribute__((ext_vector_type(8))) short bf16x8;
typedef __attribute__((ext_vector_type(4))) float f32x4;

__device__ __forceinline__ unsigned short bfc(float x) {
    return __builtin_bit_cast(unsigned short, __float2bfloat16(x));
}
__device__ __forceinline__ unsigned int pk_bf16(float a, float b) {
    return (unsigned int)bfc(a) | ((unsigned int)bfc(b) << 16);
}
__device__ __forceinline__ float lo_f(unsigned int g) {
    return __builtin_bit_cast(float, g << 16);
}
__device__ __forceinline__ float hi_f(unsigned int g) {
    return __builtin_bit_cast(float, g & 0xffff0000u);
}

// ---------------- K1: p{0,1} = X @ Wp{0,1} stored; z==2 computes p2 but only emits rr + V1T.
// z==1 epilogue also emits V0T = (p1@Wv0)^T; z==2 epilogue emits V1T = (p2@Wv1)^T.
__global__ __launch_bounds__(256) void proj_kernel(
    const float* __restrict__ X,
    const float* __restrict__ Wp0, const float* __restrict__ Wp1, const float* __restrict__ Wp2,
    const float* __restrict__ Wv0, const float* __restrict__ Wv1,
    unsigned short* __restrict__ p0b, unsigned short* __restrict__ p1b,
    unsigned short* __restrict__ V0T, unsigned short* __restrict__ V1T,
    float* __restrict__ rr)
{
    __shared__ __align__(16) unsigned short As[32][72];
    __shared__ __align__(16) unsigned short Bs[64][72];
    __shared__ float Ls[64][69];
    __shared__ float sRS[4][32];
    const int z = blockIdx.z;
    const float* W = (z == 0) ? Wp0 : (z == 1) ? Wp1 : Wp2;
    const int m0 = blockIdx.y * 32, n0 = blockIdx.x * 64;
    const int tid = threadIdx.x;
    const int w = tid >> 6, lane = tid & 63, quad = lane >> 4, l16 = lane & 15;
    f32x4 acc[2];
    #pragma unroll
    for (int mt = 0; mt < 2; ++mt) acc[mt] = (f32x4){0.f, 0.f, 0.f, 0.f};

    for (int k0 = 0; k0 < 512; k0 += 64) {
        __syncthreads();
        {
            const int row = tid >> 3, c8 = (tid & 7) * 8;
            const float4 a = *(const float4*)&X[(size_t)(m0 + row) * 512 + k0 + c8];
            const float4 b = *(const float4*)&X[(size_t)(m0 + row) * 512 + k0 + c8 + 4];
            uint4 o;
            o.x = pk_bf16(a.x, a.y);
            o.y = pk_bf16(a.z, a.w);
            o.z = pk_bf16(b.x, b.y);
            o.w = pk_bf16(b.z, b.w);
            *(uint4*)&As[row][c8] = o;
        }
        #pragma unroll
        for (int it = 0; it < 4; ++it) {
            const int q = tid + it * 256;
            const int row = q >> 4, c4 = (q & 15) * 4;
            const float4 v = *(const float4*)&W[(size_t)(k0 + row) * 512 + n0 + c4];
            Ls[row][c4 + 0] = v.x; Ls[row][c4 + 1] = v.y;
            Ls[row][c4 + 2] = v.z; Ls[row][c4 + 3] = v.w;
        }
        __syncthreads();
        #pragma unroll
        for (int it = 0; it < 2; ++it) {
            const int q = tid + it * 256;
            const int nrow = q >> 3, k8 = (q & 7) * 8;
            uint4 o;
            o.x = pk_bf16(Ls[k8 + 0][nrow], Ls[k8 + 1][nrow]);
            o.y = pk_bf16(Ls[k8 + 2][nrow], Ls[k8 + 3][nrow]);
            o.z = pk_bf16(Ls[k8 + 4][nrow], Ls[k8 + 5][nrow]);
            o.w = pk_bf16(Ls[k8 + 6][nrow], Ls[k8 + 7][nrow]);
            *(uint4*)&Bs[nrow][k8] = o;
        }
        __syncthreads();
        #pragma unroll
        for (int kt = 0; kt < 2; ++kt) {
            const bf16x8 b8 = *(const bf16x8*)&Bs[w * 16 + l16][kt * 32 + quad * 8];
            #pragma unroll
            for (int mt = 0; mt < 2; ++mt) {
                const bf16x8 a8 = *(const bf16x8*)&As[mt * 16 + l16][kt * 32 + quad * 8];
                acc[mt] = __builtin_amdgcn_mfma_f32_16x16x32_bf16(a8, b8, acc[mt], 0, 0, 0);
            }
        }
    }

    // store p0/p1 (p2 never materialized)
    if (z != 2) {
        const int n = n0 + w * 16 + l16;
        const int h = n >> 6, d = n & 63;
        unsigned short* pz = (z == 0) ? p0b : p1b;
        #pragma unroll
        for (int mt = 0; mt < 2; ++mt) {
            #pragma unroll
            for (int r = 0; r < 4; ++r) {
                const int m = m0 + mt * 16 + quad * 4 + r;
                const int bb = m >> 7, t = m & 127;
                pz[((size_t)(bb * NH + h) * T + t) * HS + d] = bfc(acc[mt][r]);
            }
        }
    }
    if (z == 2) {
        // rr = rowsums of p2
        #pragma unroll
        for (int mt = 0; mt < 2; ++mt)
            #pragma unroll
            for (int r = 0; r < 4; ++r) {
                float v = acc[mt][r];
                v += __shfl_xor(v, 1, 64); v += __shfl_xor(v, 2, 64);
                v += __shfl_xor(v, 4, 64); v += __shfl_xor(v, 8, 64);
                if (l16 == 0) sRS[w][mt * 16 + quad * 4 + r] = v;
            }
        __syncthreads();
        if (tid < 32) {
            const float s = sRS[0][tid] + sRS[1][tid] + sRS[2][tid] + sRS[3][tid];
            const int m = m0 + tid, bb = m >> 7, tl = m & 127, h = n0 >> 6;
            rr[(bb * NH + h) * T + tl] = s;
        }
    }

    // ---- V-epilogue (z==1: V0T from p1; z==2: V1T from p2) ----
    if (z >= 1) {
        const float* Wv = (z == 1) ? Wv0 : Wv1;
        unsigned short* VT = (z == 1) ? V0T : V1T;
        __syncthreads();                                   // drain main-loop As/Bs reads
        // stage acc -> As as [t][d] bf16
        #pragma unroll
        for (int mt = 0; mt < 2; ++mt)
            #pragma unroll
            for (int r = 0; r < 4; ++r)
                As[mt * 16 + quad * 4 + r][w * 16 + l16] = bfc(acc[mt][r]);
        // stage Wv^T -> Bs as [d'][d] bf16
        #pragma unroll
        for (int it = 0; it < 4; ++it) {
            const int k = (tid >> 4) + it * 16;
            const int d0 = (tid & 15) * 4;
            const float4 wv = *(const float4*)&Wv[(size_t)k * 64 + d0];
            Bs[d0 + 0][k] = bfc(wv.x); Bs[d0 + 1][k] = bfc(wv.y);
            Bs[d0 + 2][k] = bfc(wv.z); Bs[d0 + 3][k] = bfc(wv.w);
        }
        __syncthreads();
        f32x4 vacc[2];
        #pragma unroll
        for (int mt = 0; mt < 2; ++mt) vacc[mt] = (f32x4){0.f, 0.f, 0.f, 0.f};
        #pragma unroll
        for (int kt = 0; kt < 2; ++kt) {
            const bf16x8 b8 = *(const bf16x8*)&Bs[w * 16 + l16][kt * 32 + quad * 8];
            #pragma unroll
            for (int mt = 0; mt < 2; ++mt) {
                const bf16x8 a8 = *(const bf16x8*)&As[mt * 16 + l16][kt * 32 + quad * 8];
                vacc[mt] = __builtin_amdgcn_mfma_f32_16x16x32_bf16(a8, b8, vacc[mt], 0, 0, 0);
            }
        }
        // D[m=t][n=d']: col=l16 -> d' = w*16+l16 ; row = quad*4+r -> t local; store VT[d'][t]
        const int h = n0 >> 6;
        const int bb = m0 >> 7, t0 = m0 & 127;
        const int bh = bb * NH + h;
        const int dp = w * 16 + l16;
        #pragma unroll
        for (int mt = 0; mt < 2; ++mt) {
            uint2 o;
            o.x = pk_bf16(vacc[mt][0], vacc[mt][1]);
            o.y = pk_bf16(vacc[mt][2], vacc[mt][3]);
            *(uint2*)&VT[((size_t)bh * HS + dp) * T + t0 + mt * 16 + quad * 4] = o;
        }
    }
}

// ---------------- K2: attention; 512 blocks x 512 threads; V0T/V1T precomputed -> 2 barriers total
__global__ __launch_bounds__(512, 4) void attn_kernel(
    const unsigned short* __restrict__ p0b, const unsigned short* __restrict__ p1b,
    const float* __restrict__ rr,
    const unsigned short* __restrict__ V0Tg, const unsigned short* __restrict__ V1Tg,
    unsigned short* __restrict__ Yb)
{
    __shared__ __align__(16) unsigned short sV0T[64][136];
    __shared__ __align__(16) unsigned short sV1T[64][136];
    __shared__ float sS[8][128];
    __shared__ float srr[128];
    __shared__ float sZarr[8][8];            // [qq][wave] Z partials
    __shared__ float sY[8][8][64];           // [qq][wave][d] y partials

    const int bid = blockIdx.x;
    const int bh = bid & (BH - 1);
    const int ig = bid >> 5;                 // 0..15
    const int tid = threadIdx.x;
    const int w = tid >> 6;                  // 0..7 : wave owns row-tile mt = w
    const int lane = tid & 63;
    const int quad = lane >> 4;
    const int l16 = lane & 15;

    if (tid < 128) srr[tid] = rr[bh * T + tid];

    // ---- copy V0T/V1T tiles (bh slice, [d][t] bf16, 16 KB each): 64 rows x 16 chunks ----
    #pragma unroll
    for (int it = 0; it < 2; ++it) {
        const int q = tid + it * 512;        // 0..1023
        const int row = q >> 4, c8 = (q & 15) * 8;
        *(uint4*)&sV0T[row][c8] = *(const uint4*)&V0Tg[((size_t)bh * HS + row) * T + c8];
        *(uint4*)&sV1T[row][c8] = *(const uint4*)&V1Tg[((size_t)bh * HS + row) * T + c8];
    }

    // ---- all 8 S rows (wave w covers j = w*16+l16) ----
    {
        const int qr = l16 & 7;
        const int irow = (qr & 1) ? (16 * qr + 15 - ig) : (16 * qr + ig);
        const unsigned short* ap = p0b + ((size_t)bh * T + irow) * HS + (quad << 3);
        const unsigned short* bp = p1b + (size_t)bh * T * HS + (quad << 3);
        f32x4 s0 = (f32x4){0.f, 0.f, 0.f, 0.f};
        #pragma unroll
        for (int kt = 0; kt < 2; ++kt) {
            const bf16x8 a8 = *(const bf16x8*)(ap + (kt << 5));
            const bf16x8 b0 = *(const bf16x8*)(bp + (size_t)((w << 4) + l16) * HS + (kt << 5));
            s0 = __builtin_amdgcn_mfma_f32_16x16x32_bf16(a8, b0, s0, 0, 0, 0);
        }
        if (quad < 2) {
            #pragma unroll
            for (int r = 0; r < 4; ++r)
                sS[quad * 4 + r][(w << 4) + l16] = s0[r] * 0.125f;
        }
    }
    // zero partial buffers
    #pragma unroll
    for (int it = 0; it < 8; ++it) ((float*)sY)[tid + it * 512] = 0.f;
    if (tid < 64) ((float*)sZarr)[tid] = 0.f;
    __syncthreads();                                       // bar1: everything staged

    const float L2E = 1.4426950408889634f;

    // ---- hoisted global mhat (upper bound via shift-invariance) ----
    float mhat;
    {
        float aS = 0.f;
        #pragma unroll
        for (int q = 0; q < 8; ++q) {
            aS = fmaxf(aS, fabsf(sS[q][lane]));
            aS = fmaxf(aS, fabsf(sS[q][64 + lane]));
        }
        float aR = fmaxf(fabsf(srr[lane]), fabsf(srr[64 + lane]));
        #pragma unroll
        for (int off = 32; off; off >>= 1) {
            aS = fmaxf(aS, __shfl_xor(aS, off, 64));
            aR = fmaxf(aR, __shfl_xor(aR, off, 64));
        }
        mhat = aS * aR;
    }
    const float bexp = -mhat * L2E;
    const int jrow = (w << 4) + l16;
    const int ktmax = w >> 1;

    // ---- BARRIER-FREE loop: wave w participates in qq >= w (mtmax == qq) ----
    for (int qq = 7; qq >= w; --qq) {
        const int i = (qq & 1) ? (16 * qq + 15 - ig) : (16 * qq + ig);
        const float aL = sS[qq][jrow] * L2E;
        const bool rowok = (jrow <= i);
        f32x4 acc[4];
        #pragma unroll
        for (int dt = 0; dt < 4; ++dt) acc[dt] = (f32x4){0.f, 0.f, 0.f, 0.f};
        float zacc = 0.f;

        for (int kt = 0; kt <= ktmax; ++kt) {
            const int kbase = (kt << 5) + (quad << 3);
            float rk[8];
            *(float4*)&rk[0] = *(const float4*)&srr[kbase];
            *(float4*)&rk[4] = *(const float4*)&srr[kbase + 4];
            const int dlim = rowok ? (jrow - kbase) : -1;
            float e[8];
            #pragma unroll
            for (int q = 0; q < 8; ++q) {
                const float ex = __builtin_amdgcn_exp2f(fmaf(aL, rk[q], bexp));
                e[q] = (q <= dlim) ? ex : 0.f;
                zacc += e[q];
            }
            uint4 o;
            o.x = pk_bf16(e[0], e[1]);
            o.y = pk_bf16(e[2], e[3]);
            o.z = pk_bf16(e[4], e[5]);
            o.w = pk_bf16(e[6], e[7]);
            const bf16x8 a8 = __builtin_bit_cast(bf16x8, o);
            #pragma unroll
            for (int dt = 0; dt < 4; ++dt) {
                const bf16x8 b8 = *(const bf16x8*)&sV1T[(dt << 4) + l16][(quad << 3) + (kt << 5)];
                acc[dt] = __builtin_amdgcn_mfma_f32_16x16x32_bf16(a8, b8, acc[dt], 0, 0, 0);
            }
        }

        // ---- epilogue: partial y over this wave's row-tile, all 4 d-tiles ----
        float part[4];
        #pragma unroll
        for (int dt = 0; dt < 4; ++dt) {
            const uint2 uu = *(const uint2*)&sV0T[(dt << 4) + l16][(w << 4) + (quad << 2)];
            float p = 0.f;
            if (w < qq) {
                p = fmaf(lo_f(uu.x), acc[dt][0], p);
                p = fmaf(hi_f(uu.x), acc[dt][1], p);
                p = fmaf(lo_f(uu.y), acc[dt][2], p);
                p = fmaf(hi_f(uu.y), acc[dt][3], p);
            } else {
                const int jb = (w << 4) + (quad << 2);
                if (jb + 0 <= i) p = fmaf(lo_f(uu.x), acc[dt][0], p);
                if (jb + 1 <= i) p = fmaf(hi_f(uu.x), acc[dt][1], p);
                if (jb + 2 <= i) p = fmaf(lo_f(uu.y), acc[dt][2], p);
                if (jb + 3 <= i) p = fmaf(hi_f(uu.y), acc[dt][3], p);
            }
            p += __shfl_xor(p, 16, 64);
            p += __shfl_xor(p, 32, 64);
            part[dt] = p;
        }
        const float sel = (quad == 0) ? part[0] : (quad == 1) ? part[1] : (quad == 2) ? part[2] : part[3];
        sY[qq][w][lane] = sel;

        #pragma unroll
        for (int off = 32; off; off >>= 1) zacc += __shfl_xor(zacc, off, 64);
        if (lane == 0) sZarr[qq][w] = zacc;
    }
    __syncthreads();                                       // bar2: all partials published

    // ---- final combine + store: wave w -> qq = w, d = lane ----
    {
        const int qq = w;
        const int i = (qq & 1) ? (16 * qq + 15 - ig) : (16 * qq + ig);
        float Z = 0.f;
        #pragma unroll
        for (int ww = 0; ww < 8; ++ww) Z += sZarr[qq][ww];
        float y = 0.f;
        #pragma unroll
        for (int ww = 0; ww < 8; ++ww) y += sY[qq][ww][lane];
        const int bb = bh >> 3, hh = bh & 7;
        Yb[((size_t)(bb * T + i) * C) + hh * HS + lane] = bfc(y / Z);
    }
}

// ---------------- K3: OUT = Yb @ Wc (bf16 A, fp32 W transposed on the fly, fp32 out)
__global__ __launch_bounds__(256) void outmm_kernel(
    const unsigned short* __restrict__ Ab, const float* __restrict__ Wc,
    float* __restrict__ OUT)
{
    __shared__ __align__(16) unsigned short As[32][72];
    __shared__ __align__(16) unsigned short Bs[64][72];
    __shared__ float Ls[64][69];
    const int m0 = blockIdx.y * 32, n0 = blockIdx.x * 64;
    const int tid = threadIdx.x;
    const int w = tid >> 6, lane = tid & 63, quad = lane >> 4, l16 = lane & 15;
    f32x4 acc[2];
    #pragma unroll
    for (int mt = 0; mt < 2; ++mt) acc[mt] = (f32x4){0.f, 0.f, 0.f, 0.f};
    for (int k0 = 0; k0 < 512; k0 += 64) {
        __syncthreads();
        {
            const int row = tid >> 3, c8 = (tid & 7) * 8;
            *(uint4*)&As[row][c8] = *(const uint4*)&Ab[(size_t)(m0 + row) * 512 + k0 + c8];
        }
        #pragma unroll
        for (int it = 0; it < 4; ++it) {
            const int q = tid + it * 256;
            const int row = q >> 4, c4 = (q & 15) * 4;
            const float4 v = *(const float4*)&Wc[(size_t)(k0 + row) * 512 + n0 + c4];
            Ls[row][c4 + 0] = v.x; Ls[row][c4 + 1] = v.y;
            Ls[row][c4 + 2] = v.z; Ls[row][c4 + 3] = v.w;
        }
        __syncthreads();
        #pragma unroll
        for (int it = 0; it < 2; ++it) {
            const int q = tid + it * 256;
            const int nrow = q >> 3, k8 = (q & 7) * 8;
            uint4 o;
            o.x = pk_bf16(Ls[k8 + 0][nrow], Ls[k8 + 1][nrow]);
            o.y = pk_bf16(Ls[k8 + 2][nrow], Ls[k8 + 3][nrow]);
            o.z = pk_bf16(Ls[k8 + 4][nrow], Ls[k8 + 5][nrow]);
            o.w = pk_bf16(Ls[k8 + 6][nrow], Ls[k8 + 7][nrow]);
            *(uint4*)&Bs[nrow][k8] = o;
        }
        __syncthreads();
        #pragma unroll
        for (int kt = 0; kt < 2; ++kt) {
            const bf16x8 b8 = *(const bf16x8*)&Bs[w * 16 + l16][kt * 32 + quad * 8];
            #pragma unroll
            for (int mt = 0; mt < 2; ++mt) {
                const bf16x8 a8 = *(const bf16x8*)&As[mt * 16 + l16][kt * 32 + quad * 8];
                acc[mt] = __builtin_amdgcn_mfma_f32_16x16x32_bf16(a8, b8, acc[mt], 0, 0, 0);
            }
        }
    }
    const int n = n0 + w * 16 + l16;
    #pragma unroll
    for (int mt = 0; mt < 2; ++mt)
        #pragma unroll
        for (int r = 0; r < 4; ++r) {
            const int mrow = m0 + mt * 16 + quad * 4 + r;
            OUT[(size_t)mrow * 512 + n] = acc[mt][r];
        }
}

extern "C" void kernel_launch(void* const* d_in, const int* in_sizes, int n_in,
                              void* d_out, int out_size, void* d_ws, size_t ws_size,
                              hipStream_t stream)
{
    const float* x   = (const float*)d_in[0];
    const float* Wp0 = (const float*)d_in[1];
    const float* Wp1 = (const float*)d_in[2];
    const float* Wp2 = (const float*)d_in[3];
    const float* Wv0 = (const float*)d_in[4];
    const float* Wv1 = (const float*)d_in[5];
    const float* Wc  = (const float*)d_in[6];
    float* out = (float*)d_out;

    char* w8 = (char*)d_ws;
    const size_t HB = 512 * 1024;
    unsigned short* p0b = (unsigned short*)(w8 + 0 * HB);
    unsigned short* p1b = (unsigned short*)(w8 + 1 * HB);
    unsigned short* V0T = (unsigned short*)(w8 + 2 * HB);
    unsigned short* V1T = (unsigned short*)(w8 + 3 * HB);
    unsigned short* Yb  = (unsigned short*)(w8 + 4 * HB);
    float*          rr  = (float*)        (w8 + 5 * HB);

    proj_kernel <<<dim3(8, 16, 3), 256, 0, stream>>>(x, Wp0, Wp1, Wp2, Wv0, Wv1,
                                                     p0b, p1b, V0T, V1T, rr);
    attn_kernel <<<dim3(512), 512, 0, stream>>>(p0b, p1b, rr, V0T, V1T, Yb);
    outmm_kernel<<<dim3(8, 16), 256, 0, stream>>>(Yb, Wc, out);
}